// Round 10
// baseline (1237.379 us; speedup 1.0000x reference)
//
#include <hip/hip_runtime.h>

// Problem: B=2, T=48, FQ=100, D=512, H=8, hd=64, DFF=2048, L=6, WSZ=8
// Nw=6, S=800, tokens=9600, windows=12, half=4
//
// Round 19: (a) attention 2-wave blocks: R9 counters showed Occupancy 35%
// (grid 960 = 3.75 blk/CU of 6 admitted) with the same issue-bound signature
// that every grid-split has fixed (R10) and every block-growth has hurt (R7).
// 128-thread blocks, one 16-row strip/wave, qt 25, grid 2400 (= 8 XCD x 300,
// h=bid&7 pinned) -> ~8 blk/CU. Identical per-wave math; staging
// re-partitioned (each lane: 2 GLD16 K + 2 GLD16 V). (b) 6 cast dispatches
// merged into 1. GEMMs / LN / launcher otherwise = R9 (1158.7us baseline).

typedef float  f4    __attribute__((ext_vector_type(4)));
typedef __bf16 bf8   __attribute__((ext_vector_type(8)));
typedef unsigned short u16x8 __attribute__((ext_vector_type(8)));
typedef unsigned short u16x4 __attribute__((ext_vector_type(4)));
typedef unsigned int   u32x2 __attribute__((ext_vector_type(2)));
typedef unsigned int   u32x4 __attribute__((ext_vector_type(4)));

__device__ __forceinline__ unsigned short f2bf(float f) {
    unsigned int u = __builtin_bit_cast(unsigned int, f);
    u += 0x7fffu + ((u >> 16) & 1u);          // round-to-nearest-even
    return (unsigned short)(u >> 16);
}
__device__ __forceinline__ float bf2f(unsigned short s) {
    return __builtin_bit_cast(float, ((unsigned int)s) << 16);
}

// async global->LDS, 16B per lane; LDS dest = wave-uniform base + lane*16
#define GLD16(gp, lp) __builtin_amdgcn_global_load_lds( \
    (const __attribute__((address_space(1))) void*)(gp), \
    (__attribute__((address_space(3))) void*)(lp), 16, 0, 0)

// rolled row -> source row in x (frame-level roll along T=48, frames of 100)
__device__ __forceinline__ int map_row(int r, int rshift) {
    if (!rshift) return r;
    int bb = r / 4800, rem = r % 4800;
    int tt = rem / 100, f = rem - tt * 100;
    return bb * 4800 + ((tt + rshift) % 48) * 100 + f;
}

// ---------------------------------------------------------------------------
// R3 GEMM: BK=32, 3-buffer ring, 2-ahead prefetch, counted vmcnt, 1-D grid
// XCD-grouped. Used for qkv / Wo / Wp.
// ---------------------------------------------------------------------------
template<int BM>
__global__ __launch_bounds__(256) void mfma_gemm(
    const unsigned short* __restrict__ A, const unsigned short* __restrict__ W,
    const float* __restrict__ bias, float* Cf, unsigned short* Cb,
    int M, int N, int K, int relu, int rshift, int qscale, int NB)
{
    constexpr int MI      = BM / 32;
    constexpr int ABUF    = BM * 32;
    constexpr int SB      = ABUF + 4096;
    constexpr int AROUNDS = BM / 64;
    __shared__ unsigned short Ls[3 * SB];
    const int tid = threadIdx.x, lane = tid & 63, wave = tid >> 6;

    const int per = gridDim.x >> 3;
    const int l = (blockIdx.x & 7) * per + (blockIdx.x >> 3);
    const int MB = M / BM;
    if (l >= NB * MB) return;
    const int n0 = (l % NB) * 128, m0 = (l / NB) * BM;

    const unsigned short* ga[AROUNDS];
    #pragma unroll
    for (int it = 0; it < AROUNDS; ++it) {
        int s = it * 256 + tid, row = s >> 2, cg = (s & 3) ^ ((row >> 1) & 3);
        ga[it] = A + (size_t)map_row(m0 + row, rshift) * K + cg * 8;
    }
    const unsigned short* gb[2];
    #pragma unroll
    for (int it = 0; it < 2; ++it) {
        int s = it * 256 + tid, row = s >> 2, cg = (s & 3) ^ ((row >> 1) & 3);
        gb[it] = W + (size_t)(n0 + row) * K + cg * 8;
    }

    const int wm = (wave >> 1) * (BM / 2), wn = (wave & 1) * 64;
    const int lr = lane & 15, quad = lane >> 4;

    auto STAGE = [&](int kt2, int buf) {
        const int k1 = kt2 << 5;
        unsigned short* Lb = &Ls[buf * SB];
        #pragma unroll
        for (int it = 0; it < AROUNDS; ++it)
            GLD16(ga[it] + k1, &Lb[(it * 256 + wave * 64) * 8]);
        #pragma unroll
        for (int it = 0; it < 2; ++it)
            GLD16(gb[it] + k1, &Lb[ABUF + (it * 256 + wave * 64) * 8]);
    };

    f4 acc[MI][4];
    #pragma unroll
    for (int i = 0; i < MI; ++i)
        #pragma unroll
        for (int j = 0; j < 4; ++j) acc[i][j] = 0.f;

    const int NK = K >> 5;
    STAGE(0, 0);
    STAGE(1, 1);

    int cb = 0;
    for (int kt = 0; kt < NK; ++kt) {
        if (kt + 1 < NK) {
            if constexpr (BM == 128) asm volatile("s_waitcnt vmcnt(4)" ::: "memory");
            else                     asm volatile("s_waitcnt vmcnt(3)" ::: "memory");
        } else {
            asm volatile("s_waitcnt vmcnt(0)" ::: "memory");
        }
        __builtin_amdgcn_s_barrier();
        __builtin_amdgcn_sched_barrier(0);
        const int ib = (cb == 0) ? 2 : cb - 1;
        if (kt + 2 < NK) STAGE(kt + 2, ib);

        const unsigned short* Ab = &Ls[cb * SB];
        const unsigned short* Bb = &Ls[cb * SB + ABUF];
        bf8 af[MI], bfr[4];
        #pragma unroll
        for (int mi = 0; mi < MI; ++mi) {
            int m = wm + mi * 16 + lr;
            int c = quad ^ ((m >> 1) & 3);
            af[mi] = __builtin_bit_cast(bf8, *(const u16x8*)&Ab[(m * 4 + c) * 8]);
        }
        #pragma unroll
        for (int ni = 0; ni < 4; ++ni) {
            int n = wn + ni * 16 + lr;
            int c = quad ^ ((n >> 1) & 3);
            bfr[ni] = __builtin_bit_cast(bf8, *(const u16x8*)&Bb[(n * 4 + c) * 8]);
        }
        #pragma unroll
        for (int mi = 0; mi < MI; ++mi)
            #pragma unroll
            for (int ni = 0; ni < 4; ++ni)
                acc[mi][ni] = __builtin_amdgcn_mfma_f32_16x16x32_bf16(
                    af[mi], bfr[ni], acc[mi][ni], 0, 0, 0);
        __builtin_amdgcn_sched_barrier(0);
        cb = (cb + 1 == 3) ? 0 : cb + 1;
    }

    #pragma unroll
    for (int mi = 0; mi < MI; ++mi) {
        #pragma unroll
        for (int ni = 0; ni < 4; ++ni) {
            const int rowg = m0 + wm + mi * 16 + quad * 4;
            const int colg = n0 + wn + ni * 16 + lr;
            const float bv = bias[colg];
            const float sc = (qscale && colg < 512) ? 0.125f : 1.0f;
            #pragma unroll
            for (int r = 0; r < 4; ++r) {
                float v = (acc[mi][ni][r] + bv) * sc;
                if (relu) v = fmaxf(v, 0.f);
                const size_t off = (size_t)(rowg + r) * N + colg;
                if (Cf) Cf[off] = v;
                if (Cb) Cb[off] = f2bf(v);
            }
        }
    }
}

// ---------------------------------------------------------------------------
// R0 GEMM (verbatim, measured 43.9us on W1): BK=64, double-buffered LDS,
// single __syncthreads per iter, 2-D grid. Used for W1 / W2.
// ---------------------------------------------------------------------------
template<int BM>
__global__ __launch_bounds__(256) void gemm_bk64(
    const unsigned short* __restrict__ A, const unsigned short* __restrict__ W,
    const float* __restrict__ bias, float* Cf, unsigned short* Cb,
    int M, int N, int K, int relu, int rshift, int qscale)
{
    constexpr int MI      = BM / 32;
    constexpr int ABUF    = BM * 64;
    constexpr int AROUNDS = BM / 32;
    __shared__ unsigned short As[2 * ABUF];
    __shared__ unsigned short Bs[2 * 8192];
    const int tid = threadIdx.x, lane = tid & 63, wave = tid >> 6;
    const int n0 = blockIdx.x * 128, m0 = blockIdx.y * BM;

    const unsigned short* ga[AROUNDS];
    unsigned short* la[AROUNDS];
    #pragma unroll
    for (int it = 0; it < AROUNDS; ++it) {
        int s = it * 256 + tid, row = s >> 3, cg = (s & 7) ^ (row & 7);
        ga[it] = A + (size_t)map_row(m0 + row, rshift) * K + cg * 8;
        la[it] = &As[(it * 256 + wave * 64) * 8];
    }
    const unsigned short* gb[4];
    unsigned short* lb[4];
    #pragma unroll
    for (int it = 0; it < 4; ++it) {
        int s = it * 256 + tid, row = s >> 3, cg = (s & 7) ^ (row & 7);
        gb[it] = W + (size_t)(n0 + row) * K + cg * 8;
        lb[it] = &Bs[(it * 256 + wave * 64) * 8];
    }

    const int wm = (wave >> 1) * (BM / 2), wn = (wave & 1) * 64;
    const int lr = lane & 15, quad = lane >> 4;

    f4 acc[MI][4];
    #pragma unroll
    for (int i = 0; i < MI; ++i)
        #pragma unroll
        for (int j = 0; j < 4; ++j) acc[i][j] = 0.f;

    #pragma unroll
    for (int it = 0; it < AROUNDS; ++it) GLD16(ga[it], la[it]);
    #pragma unroll
    for (int it = 0; it < 4; ++it) GLD16(gb[it], lb[it]);

    const int NK = K >> 6;
    for (int kt = 0; kt < NK; ++kt) {
        const int cb = kt & 1, nb = cb ^ 1;
        __syncthreads();                   // tile kt resident; buffer nb free
        if (kt + 1 < NK) {
            const int k1 = (kt + 1) << 6;
            #pragma unroll
            for (int it = 0; it < AROUNDS; ++it) GLD16(ga[it] + k1, la[it] + nb * ABUF);
            #pragma unroll
            for (int it = 0; it < 4; ++it)       GLD16(gb[it] + k1, lb[it] + nb * 8192);
        }
        const unsigned short* Ab = &As[cb * ABUF];
        const unsigned short* Bb = &Bs[cb * 8192];
        #pragma unroll
        for (int kh = 0; kh < 2; ++kh) {
            bf8 af[MI], bfr[4];
            #pragma unroll
            for (int mi = 0; mi < MI; ++mi) {
                int m = wm + mi * 16 + lr;
                int c = (kh * 4 + quad) ^ (m & 7);
                af[mi] = __builtin_bit_cast(bf8, *(const u16x8*)&Ab[(m * 8 + c) * 8]);
            }
            #pragma unroll
            for (int ni = 0; ni < 4; ++ni) {
                int n = wn + ni * 16 + lr;
                int c = (kh * 4 + quad) ^ (n & 7);
                bfr[ni] = __builtin_bit_cast(bf8, *(const u16x8*)&Bb[(n * 8 + c) * 8]);
            }
            #pragma unroll
            for (int mi = 0; mi < MI; ++mi)
                #pragma unroll
                for (int ni = 0; ni < 4; ++ni)
                    acc[mi][ni] = __builtin_amdgcn_mfma_f32_16x16x32_bf16(
                        af[mi], bfr[ni], acc[mi][ni], 0, 0, 0);
        }
    }

    #pragma unroll
    for (int mi = 0; mi < MI; ++mi) {
        #pragma unroll
        for (int ni = 0; ni < 4; ++ni) {
            const int rowg = m0 + wm + mi * 16 + quad * 4;
            const int colg = n0 + wn + ni * 16 + lr;
            const float bv = bias[colg];
            const float sc = (qscale && colg < 512) ? 0.125f : 1.0f;
            #pragma unroll
            for (int r = 0; r < 4; ++r) {
                float v = (acc[mi][ni][r] + bv) * sc;
                if (relu) v = fmaxf(v, 0.f);
                const size_t off = (size_t)(rowg + r) * N + colg;
                if (Cf) Cf[off] = v;
                if (Cb) Cb[off] = f2bf(v);
            }
        }
    }
}

// ---------------------------------------------------------------------------
// MFMA flash attention, max-free softmax, S^T layout, KVBLK=32, 2-wave
// blocks. Each wave owns ONE 16-row Q strip (qb = qt*32 + wave*16).
// Grid = 2400 (8 XCD x 300), XCD-pinned: h = bid&7, qt = r%25, w = r/25.
// K staged swizzled-chunk; V staged via GLD16 into subtiled LDS
// (pre-swizzled global source), PV B-frags via ds_read_b64_tr_b16.
// Each lane issues 2 K-chunks + 2 V-chunks (chunk ids tid and 128+tid).
// ---------------------------------------------------------------------------
__global__ __launch_bounds__(128) void flash_attn_mfma(
    const unsigned short* __restrict__ qkv, unsigned short* __restrict__ o,
    int masked)
{
    __shared__ unsigned short Ks[2][2048];                 // K: 32x64, swizzled chunks
    __shared__ __align__(16) unsigned short VTs[2][2048];  // V: subtiled
    __shared__ unsigned short Ps[2][576];                  // per-wave P [q][key] s36

    const int bid = blockIdx.x;
    const int h = bid & 7, r2 = bid >> 3;
    const int qt = r2 % 25, w = r2 / 25;
    const int tid = threadIdx.x, lane = tid & 63, wave = tid >> 6;   // wave 0..1
    const int lr = lane & 15, quad = lane >> 4;
    const int qb = qt * 32 + wave * 16;
    const size_t wbase = (size_t)w * 800 * 1536;
    const bool do_mask = masked && ((w % 6) == 0);

    // Q B-frags (pre-scaled by 1/8): aQ[kh] = Q[qb+lr][kh*32+quad*8..]
    bf8 aQ[2];
    {
        const unsigned short* qp =
            qkv + wbase + (size_t)(qb + lr) * 1536 + h * 64 + quad * 8;
        aQ[0] = __builtin_bit_cast(bf8, *(const u16x8*)qp);
        aQ[1] = __builtin_bit_cast(bf8, *(const u16x8*)(qp + 32));
    }

    // K staging: 256 swizzled 16B chunks over 128 lanes, 2 per lane.
    // chunk c: row = c>>3, cg = (c&7)^(row&7)
    const int c0 = tid, c1 = 128 + tid;
    const unsigned short* gk0 = qkv + wbase + (size_t)(c0 >> 3) * 1536 + 512
                              + h * 64 + ((c0 & 7) ^ ((c0 >> 3) & 7)) * 8;
    const unsigned short* gk1 = qkv + wbase + (size_t)(c1 >> 3) * 1536 + 512
                              + h * 64 + ((c1 & 7) ^ ((c1 >> 3) & 7)) * 8;
    // V staging: pre-swizzled source for subtiled LDS.
    // chunk c: S=c>>3, wc=c&7 -> key = 8*(S&3)+4*((S>>2)&1)+(wc>>1),
    //                            dim0 = 16*(S>>3)+8*(wc&1)
    auto vsrc = [&](int c) {
        int S = c >> 3, wc = c & 7;
        int vkey = 8 * (S & 3) + 4 * ((S >> 2) & 1) + (wc >> 1);
        int vdim = 16 * (S >> 3) + 8 * (wc & 1);
        return qkv + wbase + (size_t)vkey * 1536 + 1024 + h * 64 + vdim;
    };
    const unsigned short* gv0 = vsrc(c0);
    const unsigned short* gv1 = vsrc(c1);

    // tr-read per-lane LDS address (64-bit slot per lane)
    unsigned vtb;
    {
        auto p3 = (__attribute__((address_space(3))) unsigned short*)&VTs[0][0];
        vtb = (unsigned)(unsigned long long)p3 + (unsigned)(lane << 3);
    }

    float lsum = 0.f;
    f4 oacc[4];
    #pragma unroll
    for (int dt = 0; dt < 4; ++dt) oacc[dt] = 0.f;

    const bool qhl = (qb + lr) >= 400;

    // prologue: stage tile 0 into buffer 0 (issue-1 chunks = wave*64 base,
    // issue-2 chunks = 128 + wave*64 base; GLD16 adds lane*16B)
    GLD16(gk0, &Ks[0][(wave * 64) * 8]);
    GLD16(gk1, &Ks[0][(128 + wave * 64) * 8]);
    GLD16(gv0, &VTs[0][(wave * 64) * 8]);
    GLD16(gv1, &VTs[0][(128 + wave * 64) * 8]);

    for (int kt = 0; kt < 25; ++kt) {
        const int cb = kt & 1, nb = cb ^ 1;
        const int k0 = kt * 32;
        __syncthreads();                     // tile kt resident (vmcnt drained)

        // prefetch tile kt+1 (async, K and V)
        if (kt < 24) {
            const size_t adv = (size_t)(k0 + 32) * 1536;
            GLD16(gk0 + adv, &Ks[nb][(wave * 64) * 8]);
            GLD16(gk1 + adv, &Ks[nb][(128 + wave * 64) * 8]);
            GLD16(gv0 + adv, &VTs[nb][(wave * 64) * 8]);
            GLD16(gv1 + adv, &VTs[nb][(128 + wave * 64) * 8]);
        }

        // S^T: A = K-frags (keys lr / 16+lr), B = Q-frag (shared reads)
        f4 st[2];                            // [keyhalf]
        st[0] = 0.f; st[1] = 0.f;
        __builtin_amdgcn_s_setprio(1);
        #pragma unroll
        for (int kh = 0; kh < 2; ++kh) {
            const int cx = (kh * 4 + quad) ^ (lane & 7);
            bf8 kf0 = __builtin_bit_cast(bf8, *(const u16x8*)&Ks[cb][(lr * 8 + cx) * 8]);
            bf8 kf1 = __builtin_bit_cast(bf8, *(const u16x8*)&Ks[cb][((16 + lr) * 8 + cx) * 8]);
            st[0] = __builtin_amdgcn_mfma_f32_16x16x32_bf16(kf0, aQ[kh], st[0], 0, 0, 0);
            st[1] = __builtin_amdgcn_mfma_f32_16x16x32_bf16(kf1, aQ[kh], st[1], 0, 0, 0);
        }
        __builtin_amdgcn_s_setprio(0);

        // max-free softmax; lane holds q=qb+lr, keys k0+quad*4+r (+16)
        {
            u16x4 pk0, pk1;
            float ls = 0.f;
            #pragma unroll
            for (int r = 0; r < 4; ++r) {
                float a = st[0][r], b = st[1][r];
                if (do_mask) {
                    if (((k0 + quad * 4 + r) >= 400) != qhl)      a -= 1000.f;
                    if (((k0 + 16 + quad * 4 + r) >= 400) != qhl) b -= 1000.f;
                }
                float p0 = __expf(fminf(a, 80.f));
                float p1 = __expf(fminf(b, 80.f));
                ls += p0 + p1;
                pk0[r] = (unsigned short)(__builtin_bit_cast(unsigned int, p0) >> 16);
                pk1[r] = (unsigned short)(__builtin_bit_cast(unsigned int, p1) >> 16);
            }
            lsum += ls;
            *(u16x4*)&Ps[wave][lr * 36 + quad * 4]      = pk0;  // b64 write
            *(u16x4*)&Ps[wave][lr * 36 + 16 + quad * 4] = pk1;  // b64 write
        }

        // PV: aP readback (same wave: ds-ordered) + V fragments via tr reads
        bf8 aP = __builtin_bit_cast(bf8, *(const u16x8*)&Ps[wave][lr * 36 + quad * 8]);
        const unsigned va = vtb + ((unsigned)cb << 12);
        u32x2 t0, t1, t2, t3, t4, t5, t6, t7;
        asm volatile("ds_read_b64_tr_b16 %0, %1"             : "=v"(t0) : "v"(va));
        asm volatile("ds_read_b64_tr_b16 %0, %1 offset:512"  : "=v"(t1) : "v"(va));
        asm volatile("ds_read_b64_tr_b16 %0, %1 offset:1024" : "=v"(t2) : "v"(va));
        asm volatile("ds_read_b64_tr_b16 %0, %1 offset:1536" : "=v"(t3) : "v"(va));
        asm volatile("ds_read_b64_tr_b16 %0, %1 offset:2048" : "=v"(t4) : "v"(va));
        asm volatile("ds_read_b64_tr_b16 %0, %1 offset:2560" : "=v"(t5) : "v"(va));
        asm volatile("ds_read_b64_tr_b16 %0, %1 offset:3072" : "=v"(t6) : "v"(va));
        asm volatile("ds_read_b64_tr_b16 %0, %1 offset:3584" : "=v"(t7) : "v"(va));
        asm volatile("s_waitcnt lgkmcnt(0)" ::: "memory");    // rule #18
        __builtin_amdgcn_sched_barrier(0);
        __builtin_amdgcn_s_setprio(1);
        {
            u32x4 b0 = {t0[0], t0[1], t1[0], t1[1]};
            u32x4 b1 = {t2[0], t2[1], t3[0], t3[1]};
            u32x4 b2 = {t4[0], t4[1], t5[0], t5[1]};
            u32x4 b3 = {t6[0], t6[1], t7[0], t7[1]};
            oacc[0] = __builtin_amdgcn_mfma_f32_16x16x32_bf16(aP, __builtin_bit_cast(bf8, b0), oacc[0], 0, 0, 0);
            oacc[1] = __builtin_amdgcn_mfma_f32_16x16x32_bf16(aP, __builtin_bit_cast(bf8, b1), oacc[1], 0, 0, 0);
            oacc[2] = __builtin_amdgcn_mfma_f32_16x16x32_bf16(aP, __builtin_bit_cast(bf8, b2), oacc[2], 0, 0, 0);
            oacc[3] = __builtin_amdgcn_mfma_f32_16x16x32_bf16(aP, __builtin_bit_cast(bf8, b3), oacc[3], 0, 0, 0);
        }
        __builtin_amdgcn_s_setprio(0);
    }

    // epilogue: l lives per lane-column q=qb+lr; O rows are q=qb+quad*4+r
    {
        float l = lsum;
        l += __shfl_xor(l, 16);
        l += __shfl_xor(l, 32);              // now equal across quads, per lr
        float inv[4];
        #pragma unroll
        for (int r = 0; r < 4; ++r)
            inv[r] = 1.0f / __shfl(l, quad * 4 + r);   // lane (quad*4+r) holds q row
        #pragma unroll
        for (int dt = 0; dt < 4; ++dt)
            #pragma unroll
            for (int r = 0; r < 4; ++r)
                o[((size_t)w * 800 + qb + quad * 4 + r) * 512 + h * 64 + dt * 16 + lr] =
                    f2bf(oacc[dt][r] * inv[r]);
    }
}

// ---------------------------------------------------------------------------
// xb[map(row)] = bf16(LN(xb[map(row)] + dlt[row]) * s + b); optional fp32 out.
// ---------------------------------------------------------------------------
__global__ __launch_bounds__(256) void add_ln_kernel(
    const unsigned short* xb, const unsigned short* dlt,
    const float* __restrict__ s, const float* __restrict__ b,
    float* outf, unsigned short* outb, int rshift)
{
    const int wave = threadIdx.x >> 6, lane = threadIdx.x & 63;
    const int row = blockIdx.x * 4 + wave;
    const int xrow = map_row(row, rshift);
    const int c = lane * 8;
    u16x8 xv = *(const u16x8*)(xb  + (size_t)xrow * 512 + c);
    u16x8 dv = *(const u16x8*)(dlt + (size_t)row  * 512 + c);
    f4 u0, u1;
    #pragma unroll
    for (int j = 0; j < 4; ++j) {
        u0[j] = bf2f(xv[j])     + bf2f(dv[j]);
        u1[j] = bf2f(xv[4 + j]) + bf2f(dv[4 + j]);
    }
    float sum = u0[0]+u0[1]+u0[2]+u0[3] + u1[0]+u1[1]+u1[2]+u1[3];
    #pragma unroll
    for (int o2 = 1; o2 < 64; o2 <<= 1) sum += __shfl_xor(sum, o2);
    const float mu = sum * (1.0f / 512.0f);
    f4 d0 = u0 - mu, d1 = u1 - mu;
    float sq = d0[0]*d0[0]+d0[1]*d0[1]+d0[2]*d0[2]+d0[3]*d0[3]
             + d1[0]*d1[0]+d1[1]*d1[1]+d1[2]*d1[2]+d1[3]*d1[3];
    #pragma unroll
    for (int o2 = 1; o2 < 64; o2 <<= 1) sq += __shfl_xor(sq, o2);
    const float rs = rsqrtf(sq * (1.0f / 512.0f) + 1e-5f);
    f4 s0 = *(const f4*)(s + c), s1 = *(const f4*)(s + c + 4);
    f4 b0 = *(const f4*)(b + c), b1 = *(const f4*)(b + c + 4);
    f4 y0, y1;
    #pragma unroll
    for (int j = 0; j < 4; ++j) { y0[j] = d0[j]*rs*s0[j]+b0[j]; y1[j] = d1[j]*rs*s1[j]+b1[j]; }
    u16x8 ob;
    #pragma unroll
    for (int j = 0; j < 4; ++j) { ob[j] = f2bf(y0[j]); ob[4+j] = f2bf(y1[j]); }
    *(u16x8*)(outb + (size_t)xrow * 512 + c) = ob;
    if (outf) {
        float* of = outf + (size_t)xrow * 512 + c;
        *(f4*)of = y0; *(f4*)(of + 4) = y1;
    }
}

// ---------------------------------------------------------------------------
// All six fp32->bf16 weight/input casts in ONE dispatch (segmented).
// Segment sizes in f4 units: fq 1228800 | Wqkv 1179648 | Wo 393216 |
// W1 1572864 | W2 1572864 | Wp 65536  (total 6012928).
// ---------------------------------------------------------------------------
__global__ __launch_bounds__(256) void cast_all_kernel(
    const float* __restrict__ fq,  const float* __restrict__ Wqkv,
    const float* __restrict__ Wo,  const float* __restrict__ W1,
    const float* __restrict__ W2,  const float* __restrict__ Wp,
    unsigned short* fqb, unsigned short* wqA, unsigned short* woA,
    unsigned short* w1A, unsigned short* w2A, unsigned short* wpA)
{
    int i = blockIdx.x * 256 + threadIdx.x;
    const float* src; unsigned short* dst;
    if (i < 1228800)                       { src = fq;   dst = fqb; }
    else if ((i -= 1228800) < 1179648)     { src = Wqkv; dst = wqA; }
    else if ((i -= 1179648) < 393216)      { src = Wo;   dst = woA; }
    else if ((i -= 393216) < 1572864)      { src = W1;   dst = w1A; }
    else if ((i -= 1572864) < 1572864)     { src = W2;   dst = w2A; }
    else if ((i -= 1572864) < 65536)       { src = Wp;   dst = wpA; }
    else return;
    f4 v = ((const f4*)src)[i];
    u16x4 o4 = {f2bf(v[0]), f2bf(v[1]), f2bf(v[2]), f2bf(v[3])};
    ((u16x4*)dst)[i] = o4;
}

// ---------------------------------------------------------------------------
extern "C" void kernel_launch(void* const* d_in, const int* in_sizes, int n_in,
                              void* d_out, int out_size, void* d_ws, size_t ws_size,
                              hipStream_t stream)
{
    const float* fq   = (const float*)d_in[0];
    const float* Wp   = (const float*)d_in[1];
    const float* bp   = (const float*)d_in[2];
    const float* Wqkv = (const float*)d_in[3];
    const float* bqkv = (const float*)d_in[4];
    const float* Wo   = (const float*)d_in[5];
    const float* bo   = (const float*)d_in[6];
    const float* l1s  = (const float*)d_in[7];
    const float* l1b  = (const float*)d_in[8];
    const float* W1   = (const float*)d_in[9];
    const float* b1   = (const float*)d_in[10];
    const float* W2   = (const float*)d_in[11];
    const float* b2   = (const float*)d_in[12];
    const float* l2s  = (const float*)d_in[13];
    const float* l2b  = (const float*)d_in[14];
    float* out = (float*)d_out;

    // Workspace (~117 MB, shorts)
    unsigned short* xb   = (unsigned short*)d_ws;
    unsigned short* qkvb = xb + 4915200;
    unsigned short* hbuf = qkvb + 14745600;
    unsigned short* wbuf = hbuf + 19660800;
    unsigned short* obuf = hbuf;              // alias (dead before W1 writes)
    unsigned short* t1b  = qkvb;              // bf16 delta (qkvb dead post-attn)
    unsigned short* fqb  = hbuf;              // alias (used only at start)
    unsigned short* wqA = wbuf;
    unsigned short* woA = wqA + 4718592;
    unsigned short* w1A = woA + 1572864;
    unsigned short* w2A = w1A + 6291456;
    unsigned short* wpA = w2A + 6291456;

    const dim3 blk(256);
    // XCD-grouped 1-D grids (padded to multiple of 8)
    #define G8(n) dim3((((n) + 7) & ~7))
    // all pre-casts in one dispatch (6012928 f4 units)
    cast_all_kernel<<<dim3(23488), blk, 0, stream>>>(fq, Wqkv, Wo, W1, W2, Wp,
                                                     fqb, wqA, woA, w1A, w2A, wpA);
    // xb = bf16(fq @ Wp^T + bp)
    mfma_gemm<64><<<G8(600), blk, 0, stream>>>(fqb, wpA, bp, nullptr, xb,
                                               9600, 512, 512, 0, 0, 0, 4);

    for (int i = 0; i < 6; ++i) {
        const int rsh = (i & 1) ? 44 : 0;     // (t+44)%48 == (t-4)%48
        const unsigned short* wq = wqA + (size_t)i * 786432;
        const unsigned short* wo = woA + (size_t)i * 262144;
        const unsigned short* w1 = w1A + (size_t)i * 1048576;
        const unsigned short* w2 = w2A + (size_t)i * 1048576;
        // qkvb[rolled] = xb[map] @ Wqkv^T + bqkv, q-cols pre-scaled by 1/8
        mfma_gemm<128><<<G8(900), blk, 0, stream>>>(xb, wq, bqkv + i * 1536,
                                                    nullptr, qkvb, 9600, 1536, 512, 0, rsh, 1, 12);
        flash_attn_mfma<<<dim3(2400), dim3(128), 0, stream>>>(qkvb, obuf, i & 1);
        // t1b[rolled] = bf16(obuf @ Wo^T + bo)   (qkvb dead -> reuse as t1b)
        mfma_gemm<64><<<G8(600), blk, 0, stream>>>(obuf, wo, bo + i * 512,
                                                   nullptr, t1b, 9600, 512, 512, 0, 0, 0, 4);
        // xb[map] = LN(xb[map] + t1b[rolled])  (folds the roll-back)
        add_ln_kernel<<<dim3(2400), blk, 0, stream>>>(xb, t1b, l1s + i * 512, l1b + i * 512,
                                                      nullptr, xb, rsh);
        // hbuf = relu(xb @ W1^T + b1)   (R0 BK=64 kernel, 2-D grid)
        gemm_bk64<128><<<dim3(16, 75), blk, 0, stream>>>(xb, w1, b1 + i * 2048,
                                                         nullptr, hbuf, 9600, 2048, 512, 1, 0, 0);
        // t1b = bf16(hbuf @ W2^T + b2)  (R0 BK=64 kernel, 2-D grid)
        gemm_bk64<64><<<dim3(4, 150), blk, 0, stream>>>(hbuf, w2, b2 + i * 512,
                                                        nullptr, t1b, 9600, 512, 2048, 0, 0, 0);
        // xb = LN(xb + t1b); last layer also writes fp32 d_out
        add_ln_kernel<<<dim3(2400), blk, 0, stream>>>(xb, t1b, l2s + i * 512, l2b + i * 512,
                                                      (i == 5) ? out : nullptr, xb, 0);
    }
    #undef G8
}

// Round 11
// 1073.853 us; speedup vs baseline: 1.1523x; 1.1523x over previous
//
#include <hip/hip_runtime.h>

// Problem: B=2, T=48, FQ=100, D=512, H=8, hd=64, DFF=2048, L=6, WSZ=8
// Nw=6, S=800, tokens=9600, windows=12, half=4
//
// Round 20: revert attention to R9's 5-wave/320-thread form (R10's 2-wave
// split regressed: occupancy FELL 35->25% — per-CU workgroup limit — and
// per-wave staging VALU doubled). Keep R10's merged cast (neutral).
// New change: XCD-grouped 1-D grid for gemm_bk64 (W1/W2). Plain 2-D grid
// round-robins the n-blocks of one A-panel across all 8 XCDs (W1 FETCH
// 41.4MB = 3.6x ideal); grouping them on one XCD makes A-panel re-reads
// L2-hits (R3 precedent: 79->28MB). Decode-only change; GEMM math = R0.

typedef float  f4    __attribute__((ext_vector_type(4)));
typedef __bf16 bf8   __attribute__((ext_vector_type(8)));
typedef unsigned short u16x8 __attribute__((ext_vector_type(8)));
typedef unsigned short u16x4 __attribute__((ext_vector_type(4)));
typedef unsigned int   u32x2 __attribute__((ext_vector_type(2)));
typedef unsigned int   u32x4 __attribute__((ext_vector_type(4)));

__device__ __forceinline__ unsigned short f2bf(float f) {
    unsigned int u = __builtin_bit_cast(unsigned int, f);
    u += 0x7fffu + ((u >> 16) & 1u);          // round-to-nearest-even
    return (unsigned short)(u >> 16);
}
__device__ __forceinline__ float bf2f(unsigned short s) {
    return __builtin_bit_cast(float, ((unsigned int)s) << 16);
}

// async global->LDS, 16B per lane; LDS dest = wave-uniform base + lane*16
#define GLD16(gp, lp) __builtin_amdgcn_global_load_lds( \
    (const __attribute__((address_space(1))) void*)(gp), \
    (__attribute__((address_space(3))) void*)(lp), 16, 0, 0)

// rolled row -> source row in x (frame-level roll along T=48, frames of 100)
__device__ __forceinline__ int map_row(int r, int rshift) {
    if (!rshift) return r;
    int bb = r / 4800, rem = r % 4800;
    int tt = rem / 100, f = rem - tt * 100;
    return bb * 4800 + ((tt + rshift) % 48) * 100 + f;
}

// ---------------------------------------------------------------------------
// R3 GEMM: BK=32, 3-buffer ring, 2-ahead prefetch, counted vmcnt, 1-D grid
// XCD-grouped. Used for qkv / Wo / Wp.
// ---------------------------------------------------------------------------
template<int BM>
__global__ __launch_bounds__(256) void mfma_gemm(
    const unsigned short* __restrict__ A, const unsigned short* __restrict__ W,
    const float* __restrict__ bias, float* Cf, unsigned short* Cb,
    int M, int N, int K, int relu, int rshift, int qscale, int NB)
{
    constexpr int MI      = BM / 32;
    constexpr int ABUF    = BM * 32;
    constexpr int SB      = ABUF + 4096;
    constexpr int AROUNDS = BM / 64;
    __shared__ unsigned short Ls[3 * SB];
    const int tid = threadIdx.x, lane = tid & 63, wave = tid >> 6;

    const int per = gridDim.x >> 3;
    const int l = (blockIdx.x & 7) * per + (blockIdx.x >> 3);
    const int MB = M / BM;
    if (l >= NB * MB) return;
    const int n0 = (l % NB) * 128, m0 = (l / NB) * BM;

    const unsigned short* ga[AROUNDS];
    #pragma unroll
    for (int it = 0; it < AROUNDS; ++it) {
        int s = it * 256 + tid, row = s >> 2, cg = (s & 3) ^ ((row >> 1) & 3);
        ga[it] = A + (size_t)map_row(m0 + row, rshift) * K + cg * 8;
    }
    const unsigned short* gb[2];
    #pragma unroll
    for (int it = 0; it < 2; ++it) {
        int s = it * 256 + tid, row = s >> 2, cg = (s & 3) ^ ((row >> 1) & 3);
        gb[it] = W + (size_t)(n0 + row) * K + cg * 8;
    }

    const int wm = (wave >> 1) * (BM / 2), wn = (wave & 1) * 64;
    const int lr = lane & 15, quad = lane >> 4;

    auto STAGE = [&](int kt2, int buf) {
        const int k1 = kt2 << 5;
        unsigned short* Lb = &Ls[buf * SB];
        #pragma unroll
        for (int it = 0; it < AROUNDS; ++it)
            GLD16(ga[it] + k1, &Lb[(it * 256 + wave * 64) * 8]);
        #pragma unroll
        for (int it = 0; it < 2; ++it)
            GLD16(gb[it] + k1, &Lb[ABUF + (it * 256 + wave * 64) * 8]);
    };

    f4 acc[MI][4];
    #pragma unroll
    for (int i = 0; i < MI; ++i)
        #pragma unroll
        for (int j = 0; j < 4; ++j) acc[i][j] = 0.f;

    const int NK = K >> 5;
    STAGE(0, 0);
    STAGE(1, 1);

    int cb = 0;
    for (int kt = 0; kt < NK; ++kt) {
        if (kt + 1 < NK) {
            if constexpr (BM == 128) asm volatile("s_waitcnt vmcnt(4)" ::: "memory");
            else                     asm volatile("s_waitcnt vmcnt(3)" ::: "memory");
        } else {
            asm volatile("s_waitcnt vmcnt(0)" ::: "memory");
        }
        __builtin_amdgcn_s_barrier();
        __builtin_amdgcn_sched_barrier(0);
        const int ib = (cb == 0) ? 2 : cb - 1;
        if (kt + 2 < NK) STAGE(kt + 2, ib);

        const unsigned short* Ab = &Ls[cb * SB];
        const unsigned short* Bb = &Ls[cb * SB + ABUF];
        bf8 af[MI], bfr[4];
        #pragma unroll
        for (int mi = 0; mi < MI; ++mi) {
            int m = wm + mi * 16 + lr;
            int c = quad ^ ((m >> 1) & 3);
            af[mi] = __builtin_bit_cast(bf8, *(const u16x8*)&Ab[(m * 4 + c) * 8]);
        }
        #pragma unroll
        for (int ni = 0; ni < 4; ++ni) {
            int n = wn + ni * 16 + lr;
            int c = quad ^ ((n >> 1) & 3);
            bfr[ni] = __builtin_bit_cast(bf8, *(const u16x8*)&Bb[(n * 4 + c) * 8]);
        }
        #pragma unroll
        for (int mi = 0; mi < MI; ++mi)
            #pragma unroll
            for (int ni = 0; ni < 4; ++ni)
                acc[mi][ni] = __builtin_amdgcn_mfma_f32_16x16x32_bf16(
                    af[mi], bfr[ni], acc[mi][ni], 0, 0, 0);
        __builtin_amdgcn_sched_barrier(0);
        cb = (cb + 1 == 3) ? 0 : cb + 1;
    }

    #pragma unroll
    for (int mi = 0; mi < MI; ++mi) {
        #pragma unroll
        for (int ni = 0; ni < 4; ++ni) {
            const int rowg = m0 + wm + mi * 16 + quad * 4;
            const int colg = n0 + wn + ni * 16 + lr;
            const float bv = bias[colg];
            const float sc = (qscale && colg < 512) ? 0.125f : 1.0f;
            #pragma unroll
            for (int r = 0; r < 4; ++r) {
                float v = (acc[mi][ni][r] + bv) * sc;
                if (relu) v = fmaxf(v, 0.f);
                const size_t off = (size_t)(rowg + r) * N + colg;
                if (Cf) Cf[off] = v;
                if (Cb) Cb[off] = f2bf(v);
            }
        }
    }
}

// ---------------------------------------------------------------------------
// R0 GEMM core (BK=64, double-buffered LDS, one __syncthreads per iter) with
// XCD-grouped 1-D grid: the NB n-blocks sharing an A-panel run consecutively
// on one XCD. Used for W1 / W2.
// ---------------------------------------------------------------------------
template<int BM>
__global__ __launch_bounds__(256) void gemm_bk64(
    const unsigned short* __restrict__ A, const unsigned short* __restrict__ W,
    const float* __restrict__ bias, float* Cf, unsigned short* Cb,
    int M, int N, int K, int relu, int rshift, int qscale, int NB)
{
    constexpr int MI      = BM / 32;
    constexpr int ABUF    = BM * 64;
    constexpr int AROUNDS = BM / 32;
    __shared__ unsigned short As[2 * ABUF];
    __shared__ unsigned short Bs[2 * 8192];
    const int tid = threadIdx.x, lane = tid & 63, wave = tid >> 6;

    const int per = gridDim.x >> 3;
    const int l = (blockIdx.x & 7) * per + (blockIdx.x >> 3);
    const int MB = M / BM;
    if (l >= NB * MB) return;
    const int n0 = (l % NB) * 128, m0 = (l / NB) * BM;

    const unsigned short* ga[AROUNDS];
    unsigned short* la[AROUNDS];
    #pragma unroll
    for (int it = 0; it < AROUNDS; ++it) {
        int s = it * 256 + tid, row = s >> 3, cg = (s & 7) ^ (row & 7);
        ga[it] = A + (size_t)map_row(m0 + row, rshift) * K + cg * 8;
        la[it] = &As[(it * 256 + wave * 64) * 8];
    }
    const unsigned short* gb[4];
    unsigned short* lb[4];
    #pragma unroll
    for (int it = 0; it < 4; ++it) {
        int s = it * 256 + tid, row = s >> 3, cg = (s & 7) ^ (row & 7);
        gb[it] = W + (size_t)(n0 + row) * K + cg * 8;
        lb[it] = &Bs[(it * 256 + wave * 64) * 8];
    }

    const int wm = (wave >> 1) * (BM / 2), wn = (wave & 1) * 64;
    const int lr = lane & 15, quad = lane >> 4;

    f4 acc[MI][4];
    #pragma unroll
    for (int i = 0; i < MI; ++i)
        #pragma unroll
        for (int j = 0; j < 4; ++j) acc[i][j] = 0.f;

    #pragma unroll
    for (int it = 0; it < AROUNDS; ++it) GLD16(ga[it], la[it]);
    #pragma unroll
    for (int it = 0; it < 4; ++it) GLD16(gb[it], lb[it]);

    const int NK = K >> 6;
    for (int kt = 0; kt < NK; ++kt) {
        const int cb = kt & 1, nb = cb ^ 1;
        __syncthreads();                   // tile kt resident; buffer nb free
        if (kt + 1 < NK) {
            const int k1 = (kt + 1) << 6;
            #pragma unroll
            for (int it = 0; it < AROUNDS; ++it) GLD16(ga[it] + k1, la[it] + nb * ABUF);
            #pragma unroll
            for (int it = 0; it < 4; ++it)       GLD16(gb[it] + k1, lb[it] + nb * 8192);
        }
        const unsigned short* Ab = &As[cb * ABUF];
        const unsigned short* Bb = &Bs[cb * 8192];
        #pragma unroll
        for (int kh = 0; kh < 2; ++kh) {
            bf8 af[MI], bfr[4];
            #pragma unroll
            for (int mi = 0; mi < MI; ++mi) {
                int m = wm + mi * 16 + lr;
                int c = (kh * 4 + quad) ^ (m & 7);
                af[mi] = __builtin_bit_cast(bf8, *(const u16x8*)&Ab[(m * 8 + c) * 8]);
            }
            #pragma unroll
            for (int ni = 0; ni < 4; ++ni) {
                int n = wn + ni * 16 + lr;
                int c = (kh * 4 + quad) ^ (n & 7);
                bfr[ni] = __builtin_bit_cast(bf8, *(const u16x8*)&Bb[(n * 8 + c) * 8]);
            }
            #pragma unroll
            for (int mi = 0; mi < MI; ++mi)
                #pragma unroll
                for (int ni = 0; ni < 4; ++ni)
                    acc[mi][ni] = __builtin_amdgcn_mfma_f32_16x16x32_bf16(
                        af[mi], bfr[ni], acc[mi][ni], 0, 0, 0);
        }
    }

    #pragma unroll
    for (int mi = 0; mi < MI; ++mi) {
        #pragma unroll
        for (int ni = 0; ni < 4; ++ni) {
            const int rowg = m0 + wm + mi * 16 + quad * 4;
            const int colg = n0 + wn + ni * 16 + lr;
            const float bv = bias[colg];
            const float sc = (qscale && colg < 512) ? 0.125f : 1.0f;
            #pragma unroll
            for (int r = 0; r < 4; ++r) {
                float v = (acc[mi][ni][r] + bv) * sc;
                if (relu) v = fmaxf(v, 0.f);
                const size_t off = (size_t)(rowg + r) * N + colg;
                if (Cf) Cf[off] = v;
                if (Cb) Cb[off] = f2bf(v);
            }
        }
    }
}

// ---------------------------------------------------------------------------
// MFMA flash attention (R9 form, best measured): max-free softmax, S^T
// layout, KVBLK=32, 5-wave/320-thread blocks, grid 960, XCD-pinned h=bid&7.
// V path: GLD16 into subtiled LDS (pre-swizzled source) + ds_read_b64_tr_b16.
// ---------------------------------------------------------------------------
__global__ __launch_bounds__(320) void flash_attn_mfma(
    const unsigned short* __restrict__ qkv, unsigned short* __restrict__ o,
    int masked)
{
    __shared__ unsigned short Ks[2][2048];                 // K: 32x64, swizzled chunks
    __shared__ __align__(16) unsigned short VTs[2][2048];  // V: subtiled
    __shared__ unsigned short Ps[5][576];                  // per-wave P [q][key] s36

    const int bid = blockIdx.x;
    const int h = bid & 7, kk2 = bid >> 3;
    const int qt = kk2 % 10, w = kk2 / 10;
    const int tid = threadIdx.x, lane = tid & 63, wave = tid >> 6;
    const int lr = lane & 15, quad = lane >> 4;
    const int qb = qt * 80 + wave * 16;
    const size_t wbase = (size_t)w * 800 * 1536;
    const bool do_mask = masked && ((w % 6) == 0);

    // Q B-frags (pre-scaled by 1/8): aQ[kh] = Q[qb+lr][kh*32+quad*8..]
    bf8 aQ[2];
    {
        const unsigned short* qp =
            qkv + wbase + (size_t)(qb + lr) * 1536 + h * 64 + quad * 8;
        aQ[0] = __builtin_bit_cast(bf8, *(const u16x8*)qp);
        aQ[1] = __builtin_bit_cast(bf8, *(const u16x8*)(qp + 32));
    }

    // K staging (waves 0..3): 256 swizzled 16B chunks
    const unsigned short* gk = qkv;
    int kw = 0;
    if (wave < 4) {
        int s = wave * 64 + lane, row = s >> 3, clog = (s & 7) ^ (row & 7);
        gk = qkv + wbase + (size_t)row * 1536 + 512 + h * 64 + clog * 8;
        kw = wave * 512;
    }
    // V staging (waves 0..3): GLD16, pre-swizzled source for subtiled LDS.
    // chunk c = wave*64+lane: S=c>>3 (subtile), wc=c&7:
    //   key = 8*(S&3) + 4*((S>>2)&1) + (wc>>1), dim0 = 16*(S>>3) + 8*(wc&1)
    const unsigned short* gvp = qkv;
    if (wave < 4) {
        int c = wave * 64 + lane, S = c >> 3, wc = c & 7;
        int vkey = 8 * (S & 3) + 4 * ((S >> 2) & 1) + (wc >> 1);
        int vdim = 16 * (S >> 3) + 8 * (wc & 1);
        gvp = qkv + wbase + (size_t)vkey * 1536 + 1024 + h * 64 + vdim;
    }

    // tr-read per-lane LDS address (64-bit slot per lane)
    unsigned vtb;
    {
        auto p3 = (__attribute__((address_space(3))) unsigned short*)&VTs[0][0];
        vtb = (unsigned)(unsigned long long)p3 + (unsigned)(lane << 3);
    }

    float lsum = 0.f;
    f4 oacc[4];
    #pragma unroll
    for (int dt = 0; dt < 4; ++dt) oacc[dt] = 0.f;

    const bool qhl = (qb + lr) >= 400;

    // prologue: stage tile 0 into buffer 0
    if (wave < 4) {
        GLD16(gk, &Ks[0][kw]);
        GLD16(gvp, &VTs[0][wave * 512]);
    }

    for (int kt = 0; kt < 25; ++kt) {
        const int cb = kt & 1, nb = cb ^ 1;
        const int k0 = kt * 32;
        __syncthreads();                     // tile kt resident (vmcnt drained)

        // prefetch tile kt+1 (async, both K and V)
        const bool pf = (kt < 24);
        if (pf && wave < 4) {
            GLD16(gk  + (size_t)(k0 + 32) * 1536, &Ks[nb][kw]);
            GLD16(gvp + (size_t)(k0 + 32) * 1536, &VTs[nb][wave * 512]);
        }

        // S^T: A = K-frags (keys lr / 16+lr), B = Q-frag (shared reads)
        f4 st[2];                            // [keyhalf]
        st[0] = 0.f; st[1] = 0.f;
        __builtin_amdgcn_s_setprio(1);
        #pragma unroll
        for (int kh = 0; kh < 2; ++kh) {
            const int cx = (kh * 4 + quad) ^ (lane & 7);
            bf8 kf0 = __builtin_bit_cast(bf8, *(const u16x8*)&Ks[cb][(lr * 8 + cx) * 8]);
            bf8 kf1 = __builtin_bit_cast(bf8, *(const u16x8*)&Ks[cb][((16 + lr) * 8 + cx) * 8]);
            st[0] = __builtin_amdgcn_mfma_f32_16x16x32_bf16(kf0, aQ[kh], st[0], 0, 0, 0);
            st[1] = __builtin_amdgcn_mfma_f32_16x16x32_bf16(kf1, aQ[kh], st[1], 0, 0, 0);
        }
        __builtin_amdgcn_s_setprio(0);

        // max-free softmax; lane holds q=qb+lr, keys k0+quad*4+r (+16)
        {
            u16x4 pk0, pk1;
            float ls = 0.f;
            #pragma unroll
            for (int r = 0; r < 4; ++r) {
                float a = st[0][r], b = st[1][r];
                if (do_mask) {
                    if (((k0 + quad * 4 + r) >= 400) != qhl)      a -= 1000.f;
                    if (((k0 + 16 + quad * 4 + r) >= 400) != qhl) b -= 1000.f;
                }
                float p0 = __expf(fminf(a, 80.f));
                float p1 = __expf(fminf(b, 80.f));
                ls += p0 + p1;
                pk0[r] = (unsigned short)(__builtin_bit_cast(unsigned int, p0) >> 16);
                pk1[r] = (unsigned short)(__builtin_bit_cast(unsigned int, p1) >> 16);
            }
            lsum += ls;
            *(u16x4*)&Ps[wave][lr * 36 + quad * 4]      = pk0;  // b64 write
            *(u16x4*)&Ps[wave][lr * 36 + 16 + quad * 4] = pk1;  // b64 write
        }

        // PV: aP readback (same wave: ds-ordered) + V fragments via tr reads
        bf8 aP = __builtin_bit_cast(bf8, *(const u16x8*)&Ps[wave][lr * 36 + quad * 8]);
        const unsigned va = vtb + ((unsigned)cb << 12);
        u32x2 t0, t1, t2, t3, t4, t5, t6, t7;
        asm volatile("ds_read_b64_tr_b16 %0, %1"             : "=v"(t0) : "v"(va));
        asm volatile("ds_read_b64_tr_b16 %0, %1 offset:512"  : "=v"(t1) : "v"(va));
        asm volatile("ds_read_b64_tr_b16 %0, %1 offset:1024" : "=v"(t2) : "v"(va));
        asm volatile("ds_read_b64_tr_b16 %0, %1 offset:1536" : "=v"(t3) : "v"(va));
        asm volatile("ds_read_b64_tr_b16 %0, %1 offset:2048" : "=v"(t4) : "v"(va));
        asm volatile("ds_read_b64_tr_b16 %0, %1 offset:2560" : "=v"(t5) : "v"(va));
        asm volatile("ds_read_b64_tr_b16 %0, %1 offset:3072" : "=v"(t6) : "v"(va));
        asm volatile("ds_read_b64_tr_b16 %0, %1 offset:3584" : "=v"(t7) : "v"(va));
        asm volatile("s_waitcnt lgkmcnt(0)" ::: "memory");    // rule #18
        __builtin_amdgcn_sched_barrier(0);
        __builtin_amdgcn_s_setprio(1);
        {
            u32x4 b0 = {t0[0], t0[1], t1[0], t1[1]};
            u32x4 b1 = {t2[0], t2[1], t3[0], t3[1]};
            u32x4 b2 = {t4[0], t4[1], t5[0], t5[1]};
            u32x4 b3 = {t6[0], t6[1], t7[0], t7[1]};
            oacc[0] = __builtin_amdgcn_mfma_f32_16x16x32_bf16(aP, __builtin_bit_cast(bf8, b0), oacc[0], 0, 0, 0);
            oacc[1] = __builtin_amdgcn_mfma_f32_16x16x32_bf16(aP, __builtin_bit_cast(bf8, b1), oacc[1], 0, 0, 0);
            oacc[2] = __builtin_amdgcn_mfma_f32_16x16x32_bf16(aP, __builtin_bit_cast(bf8, b2), oacc[2], 0, 0, 0);
            oacc[3] = __builtin_amdgcn_mfma_f32_16x16x32_bf16(aP, __builtin_bit_cast(bf8, b3), oacc[3], 0, 0, 0);
        }
        __builtin_amdgcn_s_setprio(0);
    }

    // epilogue: l lives per lane-column q=qb+lr; O rows are q=qb+quad*4+r
    {
        float l = lsum;
        l += __shfl_xor(l, 16);
        l += __shfl_xor(l, 32);              // now equal across quads, per lr
        float inv[4];
        #pragma unroll
        for (int r = 0; r < 4; ++r)
            inv[r] = 1.0f / __shfl(l, quad * 4 + r);   // lane (quad*4+r) holds q row
        #pragma unroll
        for (int dt = 0; dt < 4; ++dt)
            #pragma unroll
            for (int r = 0; r < 4; ++r)
                o[((size_t)w * 800 + qb + quad * 4 + r) * 512 + h * 64 + dt * 16 + lr] =
                    f2bf(oacc[dt][r] * inv[r]);
    }
}

// ---------------------------------------------------------------------------
// xb[map(row)] = bf16(LN(xb[map(row)] + dlt[row]) * s + b); optional fp32 out.
// ---------------------------------------------------------------------------
__global__ __launch_bounds__(256) void add_ln_kernel(
    const unsigned short* xb, const unsigned short* dlt,
    const float* __restrict__ s, const float* __restrict__ b,
    float* outf, unsigned short* outb, int rshift)
{
    const int wave = threadIdx.x >> 6, lane = threadIdx.x & 63;
    const int row = blockIdx.x * 4 + wave;
    const int xrow = map_row(row, rshift);
    const int c = lane * 8;
    u16x8 xv = *(const u16x8*)(xb  + (size_t)xrow * 512 + c);
    u16x8 dv = *(const u16x8*)(dlt + (size_t)row  * 512 + c);
    f4 u0, u1;
    #pragma unroll
    for (int j = 0; j < 4; ++j) {
        u0[j] = bf2f(xv[j])     + bf2f(dv[j]);
        u1[j] = bf2f(xv[4 + j]) + bf2f(dv[4 + j]);
    }
    float sum = u0[0]+u0[1]+u0[2]+u0[3] + u1[0]+u1[1]+u1[2]+u1[3];
    #pragma unroll
    for (int o2 = 1; o2 < 64; o2 <<= 1) sum += __shfl_xor(sum, o2);
    const float mu = sum * (1.0f / 512.0f);
    f4 d0 = u0 - mu, d1 = u1 - mu;
    float sq = d0[0]*d0[0]+d0[1]*d0[1]+d0[2]*d0[2]+d0[3]*d0[3]
             + d1[0]*d1[0]+d1[1]*d1[1]+d1[2]*d1[2]+d1[3]*d1[3];
    #pragma unroll
    for (int o2 = 1; o2 < 64; o2 <<= 1) sq += __shfl_xor(sq, o2);
    const float rs = rsqrtf(sq * (1.0f / 512.0f) + 1e-5f);
    f4 s0 = *(const f4*)(s + c), s1 = *(const f4*)(s + c + 4);
    f4 b0 = *(const f4*)(b + c), b1 = *(const f4*)(b + c + 4);
    f4 y0, y1;
    #pragma unroll
    for (int j = 0; j < 4; ++j) { y0[j] = d0[j]*rs*s0[j]+b0[j]; y1[j] = d1[j]*rs*s1[j]+b1[j]; }
    u16x8 ob;
    #pragma unroll
    for (int j = 0; j < 4; ++j) { ob[j] = f2bf(y0[j]); ob[4+j] = f2bf(y1[j]); }
    *(u16x8*)(outb + (size_t)xrow * 512 + c) = ob;
    if (outf) {
        float* of = outf + (size_t)xrow * 512 + c;
        *(f4*)of = y0; *(f4*)(of + 4) = y1;
    }
}

// ---------------------------------------------------------------------------
// All six fp32->bf16 weight/input casts in ONE dispatch (segmented).
// ---------------------------------------------------------------------------
__global__ __launch_bounds__(256) void cast_all_kernel(
    const float* __restrict__ fq,  const float* __restrict__ Wqkv,
    const float* __restrict__ Wo,  const float* __restrict__ W1,
    const float* __restrict__ W2,  const float* __restrict__ Wp,
    unsigned short* fqb, unsigned short* wqA, unsigned short* woA,
    unsigned short* w1A, unsigned short* w2A, unsigned short* wpA)
{
    int i = blockIdx.x * 256 + threadIdx.x;
    const float* src; unsigned short* dst;
    if (i < 1228800)                       { src = fq;   dst = fqb; }
    else if ((i -= 1228800) < 1179648)     { src = Wqkv; dst = wqA; }
    else if ((i -= 1179648) < 393216)      { src = Wo;   dst = woA; }
    else if ((i -= 393216) < 1572864)      { src = W1;   dst = w1A; }
    else if ((i -= 1572864) < 1572864)     { src = W2;   dst = w2A; }
    else if ((i -= 1572864) < 65536)       { src = Wp;   dst = wpA; }
    else return;
    f4 v = ((const f4*)src)[i];
    u16x4 o4 = {f2bf(v[0]), f2bf(v[1]), f2bf(v[2]), f2bf(v[3])};
    ((u16x4*)dst)[i] = o4;
}

// ---------------------------------------------------------------------------
extern "C" void kernel_launch(void* const* d_in, const int* in_sizes, int n_in,
                              void* d_out, int out_size, void* d_ws, size_t ws_size,
                              hipStream_t stream)
{
    const float* fq   = (const float*)d_in[0];
    const float* Wp   = (const float*)d_in[1];
    const float* bp   = (const float*)d_in[2];
    const float* Wqkv = (const float*)d_in[3];
    const float* bqkv = (const float*)d_in[4];
    const float* Wo   = (const float*)d_in[5];
    const float* bo   = (const float*)d_in[6];
    const float* l1s  = (const float*)d_in[7];
    const float* l1b  = (const float*)d_in[8];
    const float* W1   = (const float*)d_in[9];
    const float* b1   = (const float*)d_in[10];
    const float* W2   = (const float*)d_in[11];
    const float* b2   = (const float*)d_in[12];
    const float* l2s  = (const float*)d_in[13];
    const float* l2b  = (const float*)d_in[14];
    float* out = (float*)d_out;

    // Workspace (~117 MB, shorts)
    unsigned short* xb   = (unsigned short*)d_ws;
    unsigned short* qkvb = xb + 4915200;
    unsigned short* hbuf = qkvb + 14745600;
    unsigned short* wbuf = hbuf + 19660800;
    unsigned short* obuf = hbuf;              // alias (dead before W1 writes)
    unsigned short* t1b  = qkvb;              // bf16 delta (qkvb dead post-attn)
    unsigned short* fqb  = hbuf;              // alias (used only at start)
    unsigned short* wqA = wbuf;
    unsigned short* woA = wqA + 4718592;
    unsigned short* w1A = woA + 1572864;
    unsigned short* w2A = w1A + 6291456;
    unsigned short* wpA = w2A + 6291456;

    const dim3 blk(256);
    // XCD-grouped 1-D grids (padded to multiple of 8)
    #define G8(n) dim3((((n) + 7) & ~7))
    // all pre-casts in one dispatch (6012928 f4 units)
    cast_all_kernel<<<dim3(23488), blk, 0, stream>>>(fq, Wqkv, Wo, W1, W2, Wp,
                                                     fqb, wqA, woA, w1A, w2A, wpA);
    // xb = bf16(fq @ Wp^T + bp)
    mfma_gemm<64><<<G8(600), blk, 0, stream>>>(fqb, wpA, bp, nullptr, xb,
                                               9600, 512, 512, 0, 0, 0, 4);

    for (int i = 0; i < 6; ++i) {
        const int rsh = (i & 1) ? 44 : 0;     // (t+44)%48 == (t-4)%48
        const unsigned short* wq = wqA + (size_t)i * 786432;
        const unsigned short* wo = woA + (size_t)i * 262144;
        const unsigned short* w1 = w1A + (size_t)i * 1048576;
        const unsigned short* w2 = w2A + (size_t)i * 1048576;
        // qkvb[rolled] = xb[map] @ Wqkv^T + bqkv, q-cols pre-scaled by 1/8
        mfma_gemm<128><<<G8(900), blk, 0, stream>>>(xb, wq, bqkv + i * 1536,
                                                    nullptr, qkvb, 9600, 1536, 512, 0, rsh, 1, 12);
        flash_attn_mfma<<<dim3(960), dim3(320), 0, stream>>>(qkvb, obuf, i & 1);
        // t1b[rolled] = bf16(obuf @ Wo^T + bo)   (qkvb dead -> reuse as t1b)
        mfma_gemm<64><<<G8(600), blk, 0, stream>>>(obuf, wo, bo + i * 512,
                                                   nullptr, t1b, 9600, 512, 512, 0, 0, 0, 4);
        // xb[map] = LN(xb[map] + t1b[rolled])  (folds the roll-back)
        add_ln_kernel<<<dim3(2400), blk, 0, stream>>>(xb, t1b, l1s + i * 512, l1b + i * 512,
                                                      nullptr, xb, rsh);
        // hbuf = relu(xb @ W1^T + b1)   (BK=64 kernel, XCD-grouped 1-D grid)
        gemm_bk64<128><<<G8(1200), blk, 0, stream>>>(xb, w1, b1 + i * 2048,
                                                     nullptr, hbuf, 9600, 2048, 512, 1, 0, 0, 16);
        // t1b = bf16(hbuf @ W2^T + b2)  (BK=64 kernel, XCD-grouped 1-D grid)
        gemm_bk64<64><<<G8(600), blk, 0, stream>>>(hbuf, w2, b2 + i * 512,
                                                   nullptr, t1b, 9600, 512, 2048, 0, 0, 0, 4);
        // xb = LN(xb + t1b); last layer also writes fp32 d_out
        add_ln_kernel<<<dim3(2400), blk, 0, stream>>>(xb, t1b, l2s + i * 512, l2b + i * 512,
                                                      (i == 5) ? out : nullptr, xb, 0);
    }
    #undef G8
}

// Round 13
// 1072.432 us; speedup vs baseline: 1.1538x; 1.0013x over previous
//
#include <hip/hip_runtime.h>

// Problem: B=2, T=48, FQ=100, D=512, H=8, hd=64, DFF=2048, L=6, WSZ=8
// Nw=6, S=800, tokens=9600, windows=12, half=4
//
// Round 22 (= R21 resubmit; R12 bench was an infra failure — same signature
// as R6, which a plain resubmit fixed. Kernel re-audited: grid decodes,
// bounds, barrier structure all safe; only diff vs measured R11 is the
// qkv/Wo/Wp call sites moving from the BK=32 ring to gemm_bk64).
//
// Round 21: unify ALL GEMMs on gemm_bk64 (BK=64 double-buffer, one barrier
// per K-tile, XCD-grouped 1-D grid). Head-to-head record: bk64+XCD beats the
// BK=32 ring on every shape measured (W1 43 vs 48; W2 <42.8 vs 48.2).
// Attention / LN / cast / launcher = R11 exactly (1073.9us baseline).

typedef float  f4    __attribute__((ext_vector_type(4)));
typedef __bf16 bf8   __attribute__((ext_vector_type(8)));
typedef unsigned short u16x8 __attribute__((ext_vector_type(8)));
typedef unsigned short u16x4 __attribute__((ext_vector_type(4)));
typedef unsigned int   u32x2 __attribute__((ext_vector_type(2)));
typedef unsigned int   u32x4 __attribute__((ext_vector_type(4)));

__device__ __forceinline__ unsigned short f2bf(float f) {
    unsigned int u = __builtin_bit_cast(unsigned int, f);
    u += 0x7fffu + ((u >> 16) & 1u);          // round-to-nearest-even
    return (unsigned short)(u >> 16);
}
__device__ __forceinline__ float bf2f(unsigned short s) {
    return __builtin_bit_cast(float, ((unsigned int)s) << 16);
}

// async global->LDS, 16B per lane; LDS dest = wave-uniform base + lane*16
#define GLD16(gp, lp) __builtin_amdgcn_global_load_lds( \
    (const __attribute__((address_space(1))) void*)(gp), \
    (__attribute__((address_space(3))) void*)(lp), 16, 0, 0)

// rolled row -> source row in x (frame-level roll along T=48, frames of 100)
__device__ __forceinline__ int map_row(int r, int rshift) {
    if (!rshift) return r;
    int bb = r / 4800, rem = r % 4800;
    int tt = rem / 100, f = rem - tt * 100;
    return bb * 4800 + ((tt + rshift) % 48) * 100 + f;
}

// ---------------------------------------------------------------------------
// GEMM: BK=64, double-buffered LDS, one __syncthreads per K-tile, XCD-grouped
// 1-D grid (the NB n-blocks sharing an A-panel run consecutively on one XCD).
// C[M,N] = A[M,K] @ W[N,K]^T + bias; optional relu / roll-map / q-scale.
// BM=128: LDS 64KB (2 blk/CU), 16 MFMA per phase per wave.
// BM=64:  LDS 48KB (3 blk/CU),  8 MFMA per phase per wave.
// ---------------------------------------------------------------------------
template<int BM>
__global__ __launch_bounds__(256) void gemm_bk64(
    const unsigned short* __restrict__ A, const unsigned short* __restrict__ W,
    const float* __restrict__ bias, float* Cf, unsigned short* Cb,
    int M, int N, int K, int relu, int rshift, int qscale, int NB)
{
    constexpr int MI      = BM / 32;
    constexpr int ABUF    = BM * 64;
    constexpr int AROUNDS = BM / 32;
    __shared__ unsigned short As[2 * ABUF];
    __shared__ unsigned short Bs[2 * 8192];
    const int tid = threadIdx.x, lane = tid & 63, wave = tid >> 6;

    const int per = gridDim.x >> 3;
    const int l = (blockIdx.x & 7) * per + (blockIdx.x >> 3);
    const int MB = M / BM;
    if (l >= NB * MB) return;
    const int n0 = (l % NB) * 128, m0 = (l / NB) * BM;

    const unsigned short* ga[AROUNDS];
    unsigned short* la[AROUNDS];
    #pragma unroll
    for (int it = 0; it < AROUNDS; ++it) {
        int s = it * 256 + tid, row = s >> 3, cg = (s & 7) ^ (row & 7);
        ga[it] = A + (size_t)map_row(m0 + row, rshift) * K + cg * 8;
        la[it] = &As[(it * 256 + wave * 64) * 8];
    }
    const unsigned short* gb[4];
    unsigned short* lb[4];
    #pragma unroll
    for (int it = 0; it < 4; ++it) {
        int s = it * 256 + tid, row = s >> 3, cg = (s & 7) ^ (row & 7);
        gb[it] = W + (size_t)(n0 + row) * K + cg * 8;
        lb[it] = &Bs[(it * 256 + wave * 64) * 8];
    }

    const int wm = (wave >> 1) * (BM / 2), wn = (wave & 1) * 64;
    const int lr = lane & 15, quad = lane >> 4;

    f4 acc[MI][4];
    #pragma unroll
    for (int i = 0; i < MI; ++i)
        #pragma unroll
        for (int j = 0; j < 4; ++j) acc[i][j] = 0.f;

    #pragma unroll
    for (int it = 0; it < AROUNDS; ++it) GLD16(ga[it], la[it]);
    #pragma unroll
    for (int it = 0; it < 4; ++it) GLD16(gb[it], lb[it]);

    const int NK = K >> 6;
    for (int kt = 0; kt < NK; ++kt) {
        const int cb = kt & 1, nb = cb ^ 1;
        __syncthreads();                   // tile kt resident; buffer nb free
        if (kt + 1 < NK) {
            const int k1 = (kt + 1) << 6;
            #pragma unroll
            for (int it = 0; it < AROUNDS; ++it) GLD16(ga[it] + k1, la[it] + nb * ABUF);
            #pragma unroll
            for (int it = 0; it < 4; ++it)       GLD16(gb[it] + k1, lb[it] + nb * 8192);
        }
        const unsigned short* Ab = &As[cb * ABUF];
        const unsigned short* Bb = &Bs[cb * 8192];
        #pragma unroll
        for (int kh = 0; kh < 2; ++kh) {
            bf8 af[MI], bfr[4];
            #pragma unroll
            for (int mi = 0; mi < MI; ++mi) {
                int m = wm + mi * 16 + lr;
                int c = (kh * 4 + quad) ^ (m & 7);
                af[mi] = __builtin_bit_cast(bf8, *(const u16x8*)&Ab[(m * 8 + c) * 8]);
            }
            #pragma unroll
            for (int ni = 0; ni < 4; ++ni) {
                int n = wn + ni * 16 + lr;
                int c = (kh * 4 + quad) ^ (n & 7);
                bfr[ni] = __builtin_bit_cast(bf8, *(const u16x8*)&Bb[(n * 8 + c) * 8]);
            }
            #pragma unroll
            for (int mi = 0; mi < MI; ++mi)
                #pragma unroll
                for (int ni = 0; ni < 4; ++ni)
                    acc[mi][ni] = __builtin_amdgcn_mfma_f32_16x16x32_bf16(
                        af[mi], bfr[ni], acc[mi][ni], 0, 0, 0);
        }
    }

    #pragma unroll
    for (int mi = 0; mi < MI; ++mi) {
        #pragma unroll
        for (int ni = 0; ni < 4; ++ni) {
            const int rowg = m0 + wm + mi * 16 + quad * 4;
            const int colg = n0 + wn + ni * 16 + lr;
            const float bv = bias[colg];
            const float sc = (qscale && colg < 512) ? 0.125f : 1.0f;
            #pragma unroll
            for (int r = 0; r < 4; ++r) {
                float v = (acc[mi][ni][r] + bv) * sc;
                if (relu) v = fmaxf(v, 0.f);
                const size_t off = (size_t)(rowg + r) * N + colg;
                if (Cf) Cf[off] = v;
                if (Cb) Cb[off] = f2bf(v);
            }
        }
    }
}

// ---------------------------------------------------------------------------
// MFMA flash attention (best measured form): max-free softmax, S^T layout,
// KVBLK=32, 5-wave/320-thread blocks, grid 960, XCD-pinned h=bid&7.
// V path: GLD16 into subtiled LDS (pre-swizzled source) + ds_read_b64_tr_b16.
// ---------------------------------------------------------------------------
__global__ __launch_bounds__(320) void flash_attn_mfma(
    const unsigned short* __restrict__ qkv, unsigned short* __restrict__ o,
    int masked)
{
    __shared__ unsigned short Ks[2][2048];                 // K: 32x64, swizzled chunks
    __shared__ __align__(16) unsigned short VTs[2][2048];  // V: subtiled
    __shared__ unsigned short Ps[5][576];                  // per-wave P [q][key] s36

    const int bid = blockIdx.x;
    const int h = bid & 7, kk2 = bid >> 3;
    const int qt = kk2 % 10, w = kk2 / 10;
    const int tid = threadIdx.x, lane = tid & 63, wave = tid >> 6;
    const int lr = lane & 15, quad = lane >> 4;
    const int qb = qt * 80 + wave * 16;
    const size_t wbase = (size_t)w * 800 * 1536;
    const bool do_mask = masked && ((w % 6) == 0);

    // Q B-frags (pre-scaled by 1/8): aQ[kh] = Q[qb+lr][kh*32+quad*8..]
    bf8 aQ[2];
    {
        const unsigned short* qp =
            qkv + wbase + (size_t)(qb + lr) * 1536 + h * 64 + quad * 8;
        aQ[0] = __builtin_bit_cast(bf8, *(const u16x8*)qp);
        aQ[1] = __builtin_bit_cast(bf8, *(const u16x8*)(qp + 32));
    }

    // K staging (waves 0..3): 256 swizzled 16B chunks
    const unsigned short* gk = qkv;
    int kw = 0;
    if (wave < 4) {
        int s = wave * 64 + lane, row = s >> 3, clog = (s & 7) ^ (row & 7);
        gk = qkv + wbase + (size_t)row * 1536 + 512 + h * 64 + clog * 8;
        kw = wave * 512;
    }
    // V staging (waves 0..3): GLD16, pre-swizzled source for subtiled LDS.
    // chunk c = wave*64+lane: S=c>>3 (subtile), wc=c&7:
    //   key = 8*(S&3) + 4*((S>>2)&1) + (wc>>1), dim0 = 16*(S>>3) + 8*(wc&1)
    const unsigned short* gvp = qkv;
    if (wave < 4) {
        int c = wave * 64 + lane, S = c >> 3, wc = c & 7;
        int vkey = 8 * (S & 3) + 4 * ((S >> 2) & 1) + (wc >> 1);
        int vdim = 16 * (S >> 3) + 8 * (wc & 1);
        gvp = qkv + wbase + (size_t)vkey * 1536 + 1024 + h * 64 + vdim;
    }

    // tr-read per-lane LDS address (64-bit slot per lane)
    unsigned vtb;
    {
        auto p3 = (__attribute__((address_space(3))) unsigned short*)&VTs[0][0];
        vtb = (unsigned)(unsigned long long)p3 + (unsigned)(lane << 3);
    }

    float lsum = 0.f;
    f4 oacc[4];
    #pragma unroll
    for (int dt = 0; dt < 4; ++dt) oacc[dt] = 0.f;

    const bool qhl = (qb + lr) >= 400;

    // prologue: stage tile 0 into buffer 0
    if (wave < 4) {
        GLD16(gk, &Ks[0][kw]);
        GLD16(gvp, &VTs[0][wave * 512]);
    }

    for (int kt = 0; kt < 25; ++kt) {
        const int cb = kt & 1, nb = cb ^ 1;
        const int k0 = kt * 32;
        __syncthreads();                     // tile kt resident (vmcnt drained)

        // prefetch tile kt+1 (async, both K and V)
        const bool pf = (kt < 24);
        if (pf && wave < 4) {
            GLD16(gk  + (size_t)(k0 + 32) * 1536, &Ks[nb][kw]);
            GLD16(gvp + (size_t)(k0 + 32) * 1536, &VTs[nb][wave * 512]);
        }

        // S^T: A = K-frags (keys lr / 16+lr), B = Q-frag (shared reads)
        f4 st[2];                            // [keyhalf]
        st[0] = 0.f; st[1] = 0.f;
        __builtin_amdgcn_s_setprio(1);
        #pragma unroll
        for (int kh = 0; kh < 2; ++kh) {
            const int cx = (kh * 4 + quad) ^ (lane & 7);
            bf8 kf0 = __builtin_bit_cast(bf8, *(const u16x8*)&Ks[cb][(lr * 8 + cx) * 8]);
            bf8 kf1 = __builtin_bit_cast(bf8, *(const u16x8*)&Ks[cb][((16 + lr) * 8 + cx) * 8]);
            st[0] = __builtin_amdgcn_mfma_f32_16x16x32_bf16(kf0, aQ[kh], st[0], 0, 0, 0);
            st[1] = __builtin_amdgcn_mfma_f32_16x16x32_bf16(kf1, aQ[kh], st[1], 0, 0, 0);
        }
        __builtin_amdgcn_s_setprio(0);

        // max-free softmax; lane holds q=qb+lr, keys k0+quad*4+r (+16)
        {
            u16x4 pk0, pk1;
            float ls = 0.f;
            #pragma unroll
            for (int r = 0; r < 4; ++r) {
                float a = st[0][r], b = st[1][r];
                if (do_mask) {
                    if (((k0 + quad * 4 + r) >= 400) != qhl)      a -= 1000.f;
                    if (((k0 + 16 + quad * 4 + r) >= 400) != qhl) b -= 1000.f;
                }
                float p0 = __expf(fminf(a, 80.f));
                float p1 = __expf(fminf(b, 80.f));
                ls += p0 + p1;
                pk0[r] = (unsigned short)(__builtin_bit_cast(unsigned int, p0) >> 16);
                pk1[r] = (unsigned short)(__builtin_bit_cast(unsigned int, p1) >> 16);
            }
            lsum += ls;
            *(u16x4*)&Ps[wave][lr * 36 + quad * 4]      = pk0;  // b64 write
            *(u16x4*)&Ps[wave][lr * 36 + 16 + quad * 4] = pk1;  // b64 write
        }

        // PV: aP readback (same wave: ds-ordered) + V fragments via tr reads
        bf8 aP = __builtin_bit_cast(bf8, *(const u16x8*)&Ps[wave][lr * 36 + quad * 8]);
        const unsigned va = vtb + ((unsigned)cb << 12);
        u32x2 t0, t1, t2, t3, t4, t5, t6, t7;
        asm volatile("ds_read_b64_tr_b16 %0, %1"             : "=v"(t0) : "v"(va));
        asm volatile("ds_read_b64_tr_b16 %0, %1 offset:512"  : "=v"(t1) : "v"(va));
        asm volatile("ds_read_b64_tr_b16 %0, %1 offset:1024" : "=v"(t2) : "v"(va));
        asm volatile("ds_read_b64_tr_b16 %0, %1 offset:1536" : "=v"(t3) : "v"(va));
        asm volatile("ds_read_b64_tr_b16 %0, %1 offset:2048" : "=v"(t4) : "v"(va));
        asm volatile("ds_read_b64_tr_b16 %0, %1 offset:2560" : "=v"(t5) : "v"(va));
        asm volatile("ds_read_b64_tr_b16 %0, %1 offset:3072" : "=v"(t6) : "v"(va));
        asm volatile("ds_read_b64_tr_b16 %0, %1 offset:3584" : "=v"(t7) : "v"(va));
        asm volatile("s_waitcnt lgkmcnt(0)" ::: "memory");    // rule #18
        __builtin_amdgcn_sched_barrier(0);
        __builtin_amdgcn_s_setprio(1);
        {
            u32x4 b0 = {t0[0], t0[1], t1[0], t1[1]};
            u32x4 b1 = {t2[0], t2[1], t3[0], t3[1]};
            u32x4 b2 = {t4[0], t4[1], t5[0], t5[1]};
            u32x4 b3 = {t6[0], t6[1], t7[0], t7[1]};
            oacc[0] = __builtin_amdgcn_mfma_f32_16x16x32_bf16(aP, __builtin_bit_cast(bf8, b0), oacc[0], 0, 0, 0);
            oacc[1] = __builtin_amdgcn_mfma_f32_16x16x32_bf16(aP, __builtin_bit_cast(bf8, b1), oacc[1], 0, 0, 0);
            oacc[2] = __builtin_amdgcn_mfma_f32_16x16x32_bf16(aP, __builtin_bit_cast(bf8, b2), oacc[2], 0, 0, 0);
            oacc[3] = __builtin_amdgcn_mfma_f32_16x16x32_bf16(aP, __builtin_bit_cast(bf8, b3), oacc[3], 0, 0, 0);
        }
        __builtin_amdgcn_s_setprio(0);
    }

    // epilogue: l lives per lane-column q=qb+lr; O rows are q=qb+quad*4+r
    {
        float l = lsum;
        l += __shfl_xor(l, 16);
        l += __shfl_xor(l, 32);              // now equal across quads, per lr
        float inv[4];
        #pragma unroll
        for (int r = 0; r < 4; ++r)
            inv[r] = 1.0f / __shfl(l, quad * 4 + r);   // lane (quad*4+r) holds q row
        #pragma unroll
        for (int dt = 0; dt < 4; ++dt)
            #pragma unroll
            for (int r = 0; r < 4; ++r)
                o[((size_t)w * 800 + qb + quad * 4 + r) * 512 + h * 64 + dt * 16 + lr] =
                    f2bf(oacc[dt][r] * inv[r]);
    }
}

// ---------------------------------------------------------------------------
// xb[map(row)] = bf16(LN(xb[map(row)] + dlt[row]) * s + b); optional fp32 out.
// ---------------------------------------------------------------------------
__global__ __launch_bounds__(256) void add_ln_kernel(
    const unsigned short* xb, const unsigned short* dlt,
    const float* __restrict__ s, const float* __restrict__ b,
    float* outf, unsigned short* outb, int rshift)
{
    const int wave = threadIdx.x >> 6, lane = threadIdx.x & 63;
    const int row = blockIdx.x * 4 + wave;
    const int xrow = map_row(row, rshift);
    const int c = lane * 8;
    u16x8 xv = *(const u16x8*)(xb  + (size_t)xrow * 512 + c);
    u16x8 dv = *(const u16x8*)(dlt + (size_t)row  * 512 + c);
    f4 u0, u1;
    #pragma unroll
    for (int j = 0; j < 4; ++j) {
        u0[j] = bf2f(xv[j])     + bf2f(dv[j]);
        u1[j] = bf2f(xv[4 + j]) + bf2f(dv[4 + j]);
    }
    float sum = u0[0]+u0[1]+u0[2]+u0[3] + u1[0]+u1[1]+u1[2]+u1[3];
    #pragma unroll
    for (int o2 = 1; o2 < 64; o2 <<= 1) sum += __shfl_xor(sum, o2);
    const float mu = sum * (1.0f / 512.0f);
    f4 d0 = u0 - mu, d1 = u1 - mu;
    float sq = d0[0]*d0[0]+d0[1]*d0[1]+d0[2]*d0[2]+d0[3]*d0[3]
             + d1[0]*d1[0]+d1[1]*d1[1]+d1[2]*d1[2]+d1[3]*d1[3];
    #pragma unroll
    for (int o2 = 1; o2 < 64; o2 <<= 1) sq += __shfl_xor(sq, o2);
    const float rs = rsqrtf(sq * (1.0f / 512.0f) + 1e-5f);
    f4 s0 = *(const f4*)(s + c), s1 = *(const f4*)(s + c + 4);
    f4 b0 = *(const f4*)(b + c), b1 = *(const f4*)(b + c + 4);
    f4 y0, y1;
    #pragma unroll
    for (int j = 0; j < 4; ++j) { y0[j] = d0[j]*rs*s0[j]+b0[j]; y1[j] = d1[j]*rs*s1[j]+b1[j]; }
    u16x8 ob;
    #pragma unroll
    for (int j = 0; j < 4; ++j) { ob[j] = f2bf(y0[j]); ob[4+j] = f2bf(y1[j]); }
    *(u16x8*)(outb + (size_t)xrow * 512 + c) = ob;
    if (outf) {
        float* of = outf + (size_t)xrow * 512 + c;
        *(f4*)of = y0; *(f4*)(of + 4) = y1;
    }
}

// ---------------------------------------------------------------------------
// All six fp32->bf16 weight/input casts in ONE dispatch (segmented).
// ---------------------------------------------------------------------------
__global__ __launch_bounds__(256) void cast_all_kernel(
    const float* __restrict__ fq,  const float* __restrict__ Wqkv,
    const float* __restrict__ Wo,  const float* __restrict__ W1,
    const float* __restrict__ W2,  const float* __restrict__ Wp,
    unsigned short* fqb, unsigned short* wqA, unsigned short* woA,
    unsigned short* w1A, unsigned short* w2A, unsigned short* wpA)
{
    int i = blockIdx.x * 256 + threadIdx.x;
    const float* src; unsigned short* dst;
    if (i < 1228800)                       { src = fq;   dst = fqb; }
    else if ((i -= 1228800) < 1179648)     { src = Wqkv; dst = wqA; }
    else if ((i -= 1179648) < 393216)      { src = Wo;   dst = woA; }
    else if ((i -= 393216) < 1572864)      { src = W1;   dst = w1A; }
    else if ((i -= 1572864) < 1572864)     { src = W2;   dst = w2A; }
    else if ((i -= 1572864) < 65536)       { src = Wp;   dst = wpA; }
    else return;
    f4 v = ((const f4*)src)[i];
    u16x4 o4 = {f2bf(v[0]), f2bf(v[1]), f2bf(v[2]), f2bf(v[3])};
    ((u16x4*)dst)[i] = o4;
}

// ---------------------------------------------------------------------------
extern "C" void kernel_launch(void* const* d_in, const int* in_sizes, int n_in,
                              void* d_out, int out_size, void* d_ws, size_t ws_size,
                              hipStream_t stream)
{
    const float* fq   = (const float*)d_in[0];
    const float* Wp   = (const float*)d_in[1];
    const float* bp   = (const float*)d_in[2];
    const float* Wqkv = (const float*)d_in[3];
    const float* bqkv = (const float*)d_in[4];
    const float* Wo   = (const float*)d_in[5];
    const float* bo   = (const float*)d_in[6];
    const float* l1s  = (const float*)d_in[7];
    const float* l1b  = (const float*)d_in[8];
    const float* W1   = (const float*)d_in[9];
    const float* b1   = (const float*)d_in[10];
    const float* W2   = (const float*)d_in[11];
    const float* b2   = (const float*)d_in[12];
    const float* l2s  = (const float*)d_in[13];
    const float* l2b  = (const float*)d_in[14];
    float* out = (float*)d_out;

    // Workspace (~117 MB, shorts)
    unsigned short* xb   = (unsigned short*)d_ws;
    unsigned short* qkvb = xb + 4915200;
    unsigned short* hbuf = qkvb + 14745600;
    unsigned short* wbuf = hbuf + 19660800;
    unsigned short* obuf = hbuf;              // alias (dead before W1 writes)
    unsigned short* t1b  = qkvb;              // bf16 delta (qkvb dead post-attn)
    unsigned short* fqb  = hbuf;              // alias (used only at start)
    unsigned short* wqA = wbuf;
    unsigned short* woA = wqA + 4718592;
    unsigned short* w1A = woA + 1572864;
    unsigned short* w2A = w1A + 6291456;
    unsigned short* wpA = w2A + 6291456;

    const dim3 blk(256);
    // XCD-grouped 1-D grids (padded to multiple of 8)
    #define G8(n) dim3((((n) + 7) & ~7))
    // all pre-casts in one dispatch (6012928 f4 units)
    cast_all_kernel<<<dim3(23488), blk, 0, stream>>>(fq, Wqkv, Wo, W1, W2, Wp,
                                                     fqb, wqA, woA, w1A, w2A, wpA);
    // xb = bf16(fq @ Wp^T + bp)
    gemm_bk64<64><<<G8(600), blk, 0, stream>>>(fqb, wpA, bp, nullptr, xb,
                                               9600, 512, 512, 0, 0, 0, 4);

    for (int i = 0; i < 6; ++i) {
        const int rsh = (i & 1) ? 44 : 0;     // (t+44)%48 == (t-4)%48
        const unsigned short* wq = wqA + (size_t)i * 786432;
        const unsigned short* wo = woA + (size_t)i * 262144;
        const unsigned short* w1 = w1A + (size_t)i * 1048576;
        const unsigned short* w2 = w2A + (size_t)i * 1048576;
        // qkvb[rolled] = xb[map] @ Wqkv^T + bqkv, q-cols pre-scaled by 1/8
        gemm_bk64<128><<<G8(900), blk, 0, stream>>>(xb, wq, bqkv + i * 1536,
                                                    nullptr, qkvb, 9600, 1536, 512, 0, rsh, 1, 12);
        flash_attn_mfma<<<dim3(960), dim3(320), 0, stream>>>(qkvb, obuf, i & 1);
        // t1b[rolled] = bf16(obuf @ Wo^T + bo)   (qkvb dead -> reuse as t1b)
        gemm_bk64<64><<<G8(600), blk, 0, stream>>>(obuf, wo, bo + i * 512,
                                                   nullptr, t1b, 9600, 512, 512, 0, 0, 0, 4);
        // xb[map] = LN(xb[map] + t1b[rolled])  (folds the roll-back)
        add_ln_kernel<<<dim3(2400), blk, 0, stream>>>(xb, t1b, l1s + i * 512, l1b + i * 512,
                                                      nullptr, xb, rsh);
        // hbuf = relu(xb @ W1^T + b1)
        gemm_bk64<128><<<G8(1200), blk, 0, stream>>>(xb, w1, b1 + i * 2048,
                                                     nullptr, hbuf, 9600, 2048, 512, 1, 0, 0, 16);
        // t1b = bf16(hbuf @ W2^T + b2)
        gemm_bk64<64><<<G8(600), blk, 0, stream>>>(hbuf, w2, b2 + i * 512,
                                                   nullptr, t1b, 9600, 512, 2048, 0, 0, 0, 4);
        // xb = LN(xb + t1b); last layer also writes fp32 d_out
        add_ln_kernel<<<dim3(2400), blk, 0, stream>>>(xb, t1b, l2s + i * 512, l2b + i * 512,
                                                      (i == 5) ? out : nullptr, xb, 0);
    }
    #undef G8
}

// Round 14
// 1026.011 us; speedup vs baseline: 1.2060x; 1.0452x over previous
//
#include <hip/hip_runtime.h>

// Problem: B=2, T=48, FQ=100, D=512, H=8, hd=64, DFF=2048, L=6, WSZ=8
// Nw=6, S=800, tokens=9600, windows=12, half=4
//
// Round 23: 8-wave (512-thread) blocks for the BM=128 GEMMs (qkv, W1).
// R13 counters: W1 at Occ 16.5% (~5 waves/CU; LDS admits 8) — the lockstep
// {barrier, drain, MFMA} phase has almost no co-resident waves to hide the
// drain. Same 128x128 tile, same LDS (64KB, 2 blk/CU), same barrier count,
// but 8 waves of 32x64 each -> 16 waves/CU resident (4/SIMD). Staging
// re-partitioned: 2 A-rounds + 2 B-rounds per thread. BM=64 class (Wo/W2/
// Wp) unchanged as in-run control. Everything else = R13 (1072.4us).

typedef float  f4    __attribute__((ext_vector_type(4)));
typedef __bf16 bf8   __attribute__((ext_vector_type(8)));
typedef unsigned short u16x8 __attribute__((ext_vector_type(8)));
typedef unsigned short u16x4 __attribute__((ext_vector_type(4)));
typedef unsigned int   u32x2 __attribute__((ext_vector_type(2)));
typedef unsigned int   u32x4 __attribute__((ext_vector_type(4)));

__device__ __forceinline__ unsigned short f2bf(float f) {
    unsigned int u = __builtin_bit_cast(unsigned int, f);
    u += 0x7fffu + ((u >> 16) & 1u);          // round-to-nearest-even
    return (unsigned short)(u >> 16);
}
__device__ __forceinline__ float bf2f(unsigned short s) {
    return __builtin_bit_cast(float, ((unsigned int)s) << 16);
}

// async global->LDS, 16B per lane; LDS dest = wave-uniform base + lane*16
#define GLD16(gp, lp) __builtin_amdgcn_global_load_lds( \
    (const __attribute__((address_space(1))) void*)(gp), \
    (__attribute__((address_space(3))) void*)(lp), 16, 0, 0)

// rolled row -> source row in x (frame-level roll along T=48, frames of 100)
__device__ __forceinline__ int map_row(int r, int rshift) {
    if (!rshift) return r;
    int bb = r / 4800, rem = r % 4800;
    int tt = rem / 100, f = rem - tt * 100;
    return bb * 4800 + ((tt + rshift) % 48) * 100 + f;
}

// ---------------------------------------------------------------------------
// GEMM (BM=64, 4 waves): BK=64, double-buffered LDS, one __syncthreads per
// K-tile, XCD-grouped 1-D grid. Used for Wo / Wp / W2 (unchanged control).
// ---------------------------------------------------------------------------
template<int BM>
__global__ __launch_bounds__(256) void gemm_bk64(
    const unsigned short* __restrict__ A, const unsigned short* __restrict__ W,
    const float* __restrict__ bias, float* Cf, unsigned short* Cb,
    int M, int N, int K, int relu, int rshift, int qscale, int NB)
{
    constexpr int MI      = BM / 32;
    constexpr int ABUF    = BM * 64;
    constexpr int AROUNDS = BM / 32;
    __shared__ unsigned short As[2 * ABUF];
    __shared__ unsigned short Bs[2 * 8192];
    const int tid = threadIdx.x, lane = tid & 63, wave = tid >> 6;

    const int per = gridDim.x >> 3;
    const int l = (blockIdx.x & 7) * per + (blockIdx.x >> 3);
    const int MB = M / BM;
    if (l >= NB * MB) return;
    const int n0 = (l % NB) * 128, m0 = (l / NB) * BM;

    const unsigned short* ga[AROUNDS];
    unsigned short* la[AROUNDS];
    #pragma unroll
    for (int it = 0; it < AROUNDS; ++it) {
        int s = it * 256 + tid, row = s >> 3, cg = (s & 7) ^ (row & 7);
        ga[it] = A + (size_t)map_row(m0 + row, rshift) * K + cg * 8;
        la[it] = &As[(it * 256 + wave * 64) * 8];
    }
    const unsigned short* gb[4];
    unsigned short* lb[4];
    #pragma unroll
    for (int it = 0; it < 4; ++it) {
        int s = it * 256 + tid, row = s >> 3, cg = (s & 7) ^ (row & 7);
        gb[it] = W + (size_t)(n0 + row) * K + cg * 8;
        lb[it] = &Bs[(it * 256 + wave * 64) * 8];
    }

    const int wm = (wave >> 1) * (BM / 2), wn = (wave & 1) * 64;
    const int lr = lane & 15, quad = lane >> 4;

    f4 acc[MI][4];
    #pragma unroll
    for (int i = 0; i < MI; ++i)
        #pragma unroll
        for (int j = 0; j < 4; ++j) acc[i][j] = 0.f;

    #pragma unroll
    for (int it = 0; it < AROUNDS; ++it) GLD16(ga[it], la[it]);
    #pragma unroll
    for (int it = 0; it < 4; ++it) GLD16(gb[it], lb[it]);

    const int NK = K >> 6;
    for (int kt = 0; kt < NK; ++kt) {
        const int cb = kt & 1, nb = cb ^ 1;
        __syncthreads();                   // tile kt resident; buffer nb free
        if (kt + 1 < NK) {
            const int k1 = (kt + 1) << 6;
            #pragma unroll
            for (int it = 0; it < AROUNDS; ++it) GLD16(ga[it] + k1, la[it] + nb * ABUF);
            #pragma unroll
            for (int it = 0; it < 4; ++it)       GLD16(gb[it] + k1, lb[it] + nb * 8192);
        }
        const unsigned short* Ab = &As[cb * ABUF];
        const unsigned short* Bb = &Bs[cb * 8192];
        #pragma unroll
        for (int kh = 0; kh < 2; ++kh) {
            bf8 af[MI], bfr[4];
            #pragma unroll
            for (int mi = 0; mi < MI; ++mi) {
                int m = wm + mi * 16 + lr;
                int c = (kh * 4 + quad) ^ (m & 7);
                af[mi] = __builtin_bit_cast(bf8, *(const u16x8*)&Ab[(m * 8 + c) * 8]);
            }
            #pragma unroll
            for (int ni = 0; ni < 4; ++ni) {
                int n = wn + ni * 16 + lr;
                int c = (kh * 4 + quad) ^ (n & 7);
                bfr[ni] = __builtin_bit_cast(bf8, *(const u16x8*)&Bb[(n * 8 + c) * 8]);
            }
            #pragma unroll
            for (int mi = 0; mi < MI; ++mi)
                #pragma unroll
                for (int ni = 0; ni < 4; ++ni)
                    acc[mi][ni] = __builtin_amdgcn_mfma_f32_16x16x32_bf16(
                        af[mi], bfr[ni], acc[mi][ni], 0, 0, 0);
        }
    }

    #pragma unroll
    for (int mi = 0; mi < MI; ++mi) {
        #pragma unroll
        for (int ni = 0; ni < 4; ++ni) {
            const int rowg = m0 + wm + mi * 16 + quad * 4;
            const int colg = n0 + wn + ni * 16 + lr;
            const float bv = bias[colg];
            const float sc = (qscale && colg < 512) ? 0.125f : 1.0f;
            #pragma unroll
            for (int r = 0; r < 4; ++r) {
                float v = (acc[mi][ni][r] + bv) * sc;
                if (relu) v = fmaxf(v, 0.f);
                const size_t off = (size_t)(rowg + r) * N + colg;
                if (Cf) Cf[off] = v;
                if (Cb) Cb[off] = f2bf(v);
            }
        }
    }
}

// ---------------------------------------------------------------------------
// GEMM (BM=128, 8 waves / 512 threads): same BK=64 double-buffer and barrier
// structure, but the 128x128 tile is split over 8 waves of 32x64 each ->
// 16 waves/CU resident at the same 64KB LDS (2 blk/CU). Used for qkv / W1.
// Wave layout: wm = (wave>>1)*32, wn = (wave&1)*64. MI=2, NI=4.
// Staging: A = 1024 chunks (2 rounds x 512 thr), B same.
// ---------------------------------------------------------------------------
__global__ __launch_bounds__(512) void gemm_bk64_w8(
    const unsigned short* __restrict__ A, const unsigned short* __restrict__ W,
    const float* __restrict__ bias, float* Cf, unsigned short* Cb,
    int M, int N, int K, int relu, int rshift, int qscale, int NB)
{
    __shared__ unsigned short As[2 * 8192];    // 128 rows x 64 k, swizzled chunks
    __shared__ unsigned short Bs[2 * 8192];
    const int tid = threadIdx.x, lane = tid & 63, wave = tid >> 6;   // 0..7

    const int per = gridDim.x >> 3;
    const int l = (blockIdx.x & 7) * per + (blockIdx.x >> 3);
    const int MB = M / 128;
    if (l >= NB * MB) return;
    const int n0 = (l % NB) * 128, m0 = (l / NB) * 128;

    const unsigned short* ga[2];
    unsigned short* la[2];
    #pragma unroll
    for (int it = 0; it < 2; ++it) {
        int s = it * 512 + tid, row = s >> 3, cg = (s & 7) ^ (row & 7);
        ga[it] = A + (size_t)map_row(m0 + row, rshift) * K + cg * 8;
        la[it] = &As[(it * 512 + wave * 64) * 8];
    }
    const unsigned short* gb[2];
    unsigned short* lb[2];
    #pragma unroll
    for (int it = 0; it < 2; ++it) {
        int s = it * 512 + tid, row = s >> 3, cg = (s & 7) ^ (row & 7);
        gb[it] = W + (size_t)(n0 + row) * K + cg * 8;
        lb[it] = &Bs[(it * 512 + wave * 64) * 8];
    }

    const int wm = (wave >> 1) * 32, wn = (wave & 1) * 64;
    const int lr = lane & 15, quad = lane >> 4;

    f4 acc[2][4];
    #pragma unroll
    for (int i = 0; i < 2; ++i)
        #pragma unroll
        for (int j = 0; j < 4; ++j) acc[i][j] = 0.f;

    #pragma unroll
    for (int it = 0; it < 2; ++it) { GLD16(ga[it], la[it]); GLD16(gb[it], lb[it]); }

    const int NK = K >> 6;
    for (int kt = 0; kt < NK; ++kt) {
        const int cb = kt & 1, nb = cb ^ 1;
        __syncthreads();                   // tile kt resident; buffer nb free
        if (kt + 1 < NK) {
            const int k1 = (kt + 1) << 6;
            #pragma unroll
            for (int it = 0; it < 2; ++it) {
                GLD16(ga[it] + k1, la[it] + nb * 8192);
                GLD16(gb[it] + k1, lb[it] + nb * 8192);
            }
        }
        const unsigned short* Ab = &As[cb * 8192];
        const unsigned short* Bb = &Bs[cb * 8192];
        #pragma unroll
        for (int kh = 0; kh < 2; ++kh) {
            bf8 af[2], bfr[4];
            #pragma unroll
            for (int mi = 0; mi < 2; ++mi) {
                int m = wm + mi * 16 + lr;
                int c = (kh * 4 + quad) ^ (m & 7);
                af[mi] = __builtin_bit_cast(bf8, *(const u16x8*)&Ab[(m * 8 + c) * 8]);
            }
            #pragma unroll
            for (int ni = 0; ni < 4; ++ni) {
                int n = wn + ni * 16 + lr;
                int c = (kh * 4 + quad) ^ (n & 7);
                bfr[ni] = __builtin_bit_cast(bf8, *(const u16x8*)&Bb[(n * 8 + c) * 8]);
            }
            #pragma unroll
            for (int mi = 0; mi < 2; ++mi)
                #pragma unroll
                for (int ni = 0; ni < 4; ++ni)
                    acc[mi][ni] = __builtin_amdgcn_mfma_f32_16x16x32_bf16(
                        af[mi], bfr[ni], acc[mi][ni], 0, 0, 0);
        }
    }

    #pragma unroll
    for (int mi = 0; mi < 2; ++mi) {
        #pragma unroll
        for (int ni = 0; ni < 4; ++ni) {
            const int rowg = m0 + wm + mi * 16 + quad * 4;
            const int colg = n0 + wn + ni * 16 + lr;
            const float bv = bias[colg];
            const float sc = (qscale && colg < 512) ? 0.125f : 1.0f;
            #pragma unroll
            for (int r = 0; r < 4; ++r) {
                float v = (acc[mi][ni][r] + bv) * sc;
                if (relu) v = fmaxf(v, 0.f);
                const size_t off = (size_t)(rowg + r) * N + colg;
                if (Cf) Cf[off] = v;
                if (Cb) Cb[off] = f2bf(v);
            }
        }
    }
}

// ---------------------------------------------------------------------------
// MFMA flash attention (best measured form): max-free softmax, S^T layout,
// KVBLK=32, 5-wave/320-thread blocks, grid 960, XCD-pinned h=bid&7.
// V path: GLD16 into subtiled LDS (pre-swizzled source) + ds_read_b64_tr_b16.
// ---------------------------------------------------------------------------
__global__ __launch_bounds__(320) void flash_attn_mfma(
    const unsigned short* __restrict__ qkv, unsigned short* __restrict__ o,
    int masked)
{
    __shared__ unsigned short Ks[2][2048];                 // K: 32x64, swizzled chunks
    __shared__ __align__(16) unsigned short VTs[2][2048];  // V: subtiled
    __shared__ unsigned short Ps[5][576];                  // per-wave P [q][key] s36

    const int bid = blockIdx.x;
    const int h = bid & 7, kk2 = bid >> 3;
    const int qt = kk2 % 10, w = kk2 / 10;
    const int tid = threadIdx.x, lane = tid & 63, wave = tid >> 6;
    const int lr = lane & 15, quad = lane >> 4;
    const int qb = qt * 80 + wave * 16;
    const size_t wbase = (size_t)w * 800 * 1536;
    const bool do_mask = masked && ((w % 6) == 0);

    // Q B-frags (pre-scaled by 1/8): aQ[kh] = Q[qb+lr][kh*32+quad*8..]
    bf8 aQ[2];
    {
        const unsigned short* qp =
            qkv + wbase + (size_t)(qb + lr) * 1536 + h * 64 + quad * 8;
        aQ[0] = __builtin_bit_cast(bf8, *(const u16x8*)qp);
        aQ[1] = __builtin_bit_cast(bf8, *(const u16x8*)(qp + 32));
    }

    // K staging (waves 0..3): 256 swizzled 16B chunks
    const unsigned short* gk = qkv;
    int kw = 0;
    if (wave < 4) {
        int s = wave * 64 + lane, row = s >> 3, clog = (s & 7) ^ (row & 7);
        gk = qkv + wbase + (size_t)row * 1536 + 512 + h * 64 + clog * 8;
        kw = wave * 512;
    }
    // V staging (waves 0..3): GLD16, pre-swizzled source for subtiled LDS.
    // chunk c = wave*64+lane: S=c>>3 (subtile), wc=c&7:
    //   key = 8*(S&3) + 4*((S>>2)&1) + (wc>>1), dim0 = 16*(S>>3) + 8*(wc&1)
    const unsigned short* gvp = qkv;
    if (wave < 4) {
        int c = wave * 64 + lane, S = c >> 3, wc = c & 7;
        int vkey = 8 * (S & 3) + 4 * ((S >> 2) & 1) + (wc >> 1);
        int vdim = 16 * (S >> 3) + 8 * (wc & 1);
        gvp = qkv + wbase + (size_t)vkey * 1536 + 1024 + h * 64 + vdim;
    }

    // tr-read per-lane LDS address (64-bit slot per lane)
    unsigned vtb;
    {
        auto p3 = (__attribute__((address_space(3))) unsigned short*)&VTs[0][0];
        vtb = (unsigned)(unsigned long long)p3 + (unsigned)(lane << 3);
    }

    float lsum = 0.f;
    f4 oacc[4];
    #pragma unroll
    for (int dt = 0; dt < 4; ++dt) oacc[dt] = 0.f;

    const bool qhl = (qb + lr) >= 400;

    // prologue: stage tile 0 into buffer 0
    if (wave < 4) {
        GLD16(gk, &Ks[0][kw]);
        GLD16(gvp, &VTs[0][wave * 512]);
    }

    for (int kt = 0; kt < 25; ++kt) {
        const int cb = kt & 1, nb = cb ^ 1;
        const int k0 = kt * 32;
        __syncthreads();                     // tile kt resident (vmcnt drained)

        // prefetch tile kt+1 (async, both K and V)
        const bool pf = (kt < 24);
        if (pf && wave < 4) {
            GLD16(gk  + (size_t)(k0 + 32) * 1536, &Ks[nb][kw]);
            GLD16(gvp + (size_t)(k0 + 32) * 1536, &VTs[nb][wave * 512]);
        }

        // S^T: A = K-frags (keys lr / 16+lr), B = Q-frag (shared reads)
        f4 st[2];                            // [keyhalf]
        st[0] = 0.f; st[1] = 0.f;
        __builtin_amdgcn_s_setprio(1);
        #pragma unroll
        for (int kh = 0; kh < 2; ++kh) {
            const int cx = (kh * 4 + quad) ^ (lane & 7);
            bf8 kf0 = __builtin_bit_cast(bf8, *(const u16x8*)&Ks[cb][(lr * 8 + cx) * 8]);
            bf8 kf1 = __builtin_bit_cast(bf8, *(const u16x8*)&Ks[cb][((16 + lr) * 8 + cx) * 8]);
            st[0] = __builtin_amdgcn_mfma_f32_16x16x32_bf16(kf0, aQ[kh], st[0], 0, 0, 0);
            st[1] = __builtin_amdgcn_mfma_f32_16x16x32_bf16(kf1, aQ[kh], st[1], 0, 0, 0);
        }
        __builtin_amdgcn_s_setprio(0);

        // max-free softmax; lane holds q=qb+lr, keys k0+quad*4+r (+16)
        {
            u16x4 pk0, pk1;
            float ls = 0.f;
            #pragma unroll
            for (int r = 0; r < 4; ++r) {
                float a = st[0][r], b = st[1][r];
                if (do_mask) {
                    if (((k0 + quad * 4 + r) >= 400) != qhl)      a -= 1000.f;
                    if (((k0 + 16 + quad * 4 + r) >= 400) != qhl) b -= 1000.f;
                }
                float p0 = __expf(fminf(a, 80.f));
                float p1 = __expf(fminf(b, 80.f));
                ls += p0 + p1;
                pk0[r] = (unsigned short)(__builtin_bit_cast(unsigned int, p0) >> 16);
                pk1[r] = (unsigned short)(__builtin_bit_cast(unsigned int, p1) >> 16);
            }
            lsum += ls;
            *(u16x4*)&Ps[wave][lr * 36 + quad * 4]      = pk0;  // b64 write
            *(u16x4*)&Ps[wave][lr * 36 + 16 + quad * 4] = pk1;  // b64 write
        }

        // PV: aP readback (same wave: ds-ordered) + V fragments via tr reads
        bf8 aP = __builtin_bit_cast(bf8, *(const u16x8*)&Ps[wave][lr * 36 + quad * 8]);
        const unsigned va = vtb + ((unsigned)cb << 12);
        u32x2 t0, t1, t2, t3, t4, t5, t6, t7;
        asm volatile("ds_read_b64_tr_b16 %0, %1"             : "=v"(t0) : "v"(va));
        asm volatile("ds_read_b64_tr_b16 %0, %1 offset:512"  : "=v"(t1) : "v"(va));
        asm volatile("ds_read_b64_tr_b16 %0, %1 offset:1024" : "=v"(t2) : "v"(va));
        asm volatile("ds_read_b64_tr_b16 %0, %1 offset:1536" : "=v"(t3) : "v"(va));
        asm volatile("ds_read_b64_tr_b16 %0, %1 offset:2048" : "=v"(t4) : "v"(va));
        asm volatile("ds_read_b64_tr_b16 %0, %1 offset:2560" : "=v"(t5) : "v"(va));
        asm volatile("ds_read_b64_tr_b16 %0, %1 offset:3072" : "=v"(t6) : "v"(va));
        asm volatile("ds_read_b64_tr_b16 %0, %1 offset:3584" : "=v"(t7) : "v"(va));
        asm volatile("s_waitcnt lgkmcnt(0)" ::: "memory");    // rule #18
        __builtin_amdgcn_sched_barrier(0);
        __builtin_amdgcn_s_setprio(1);
        {
            u32x4 b0 = {t0[0], t0[1], t1[0], t1[1]};
            u32x4 b1 = {t2[0], t2[1], t3[0], t3[1]};
            u32x4 b2 = {t4[0], t4[1], t5[0], t5[1]};
            u32x4 b3 = {t6[0], t6[1], t7[0], t7[1]};
            oacc[0] = __builtin_amdgcn_mfma_f32_16x16x32_bf16(aP, __builtin_bit_cast(bf8, b0), oacc[0], 0, 0, 0);
            oacc[1] = __builtin_amdgcn_mfma_f32_16x16x32_bf16(aP, __builtin_bit_cast(bf8, b1), oacc[1], 0, 0, 0);
            oacc[2] = __builtin_amdgcn_mfma_f32_16x16x32_bf16(aP, __builtin_bit_cast(bf8, b2), oacc[2], 0, 0, 0);
            oacc[3] = __builtin_amdgcn_mfma_f32_16x16x32_bf16(aP, __builtin_bit_cast(bf8, b3), oacc[3], 0, 0, 0);
        }
        __builtin_amdgcn_s_setprio(0);
    }

    // epilogue: l lives per lane-column q=qb+lr; O rows are q=qb+quad*4+r
    {
        float l = lsum;
        l += __shfl_xor(l, 16);
        l += __shfl_xor(l, 32);              // now equal across quads, per lr
        float inv[4];
        #pragma unroll
        for (int r = 0; r < 4; ++r)
            inv[r] = 1.0f / __shfl(l, quad * 4 + r);   // lane (quad*4+r) holds q row
        #pragma unroll
        for (int dt = 0; dt < 4; ++dt)
            #pragma unroll
            for (int r = 0; r < 4; ++r)
                o[((size_t)w * 800 + qb + quad * 4 + r) * 512 + h * 64 + dt * 16 + lr] =
                    f2bf(oacc[dt][r] * inv[r]);
    }
}

// ---------------------------------------------------------------------------
// xb[map(row)] = bf16(LN(xb[map(row)] + dlt[row]) * s + b); optional fp32 out.
// ---------------------------------------------------------------------------
__global__ __launch_bounds__(256) void add_ln_kernel(
    const unsigned short* xb, const unsigned short* dlt,
    const float* __restrict__ s, const float* __restrict__ b,
    float* outf, unsigned short* outb, int rshift)
{
    const int wave = threadIdx.x >> 6, lane = threadIdx.x & 63;
    const int row = blockIdx.x * 4 + wave;
    const int xrow = map_row(row, rshift);
    const int c = lane * 8;
    u16x8 xv = *(const u16x8*)(xb  + (size_t)xrow * 512 + c);
    u16x8 dv = *(const u16x8*)(dlt + (size_t)row  * 512 + c);
    f4 u0, u1;
    #pragma unroll
    for (int j = 0; j < 4; ++j) {
        u0[j] = bf2f(xv[j])     + bf2f(dv[j]);
        u1[j] = bf2f(xv[4 + j]) + bf2f(dv[4 + j]);
    }
    float sum = u0[0]+u0[1]+u0[2]+u0[3] + u1[0]+u1[1]+u1[2]+u1[3];
    #pragma unroll
    for (int o2 = 1; o2 < 64; o2 <<= 1) sum += __shfl_xor(sum, o2);
    const float mu = sum * (1.0f / 512.0f);
    f4 d0 = u0 - mu, d1 = u1 - mu;
    float sq = d0[0]*d0[0]+d0[1]*d0[1]+d0[2]*d0[2]+d0[3]*d0[3]
             + d1[0]*d1[0]+d1[1]*d1[1]+d1[2]*d1[2]+d1[3]*d1[3];
    #pragma unroll
    for (int o2 = 1; o2 < 64; o2 <<= 1) sq += __shfl_xor(sq, o2);
    const float rs = rsqrtf(sq * (1.0f / 512.0f) + 1e-5f);
    f4 s0 = *(const f4*)(s + c), s1 = *(const f4*)(s + c + 4);
    f4 b0 = *(const f4*)(b + c), b1 = *(const f4*)(b + c + 4);
    f4 y0, y1;
    #pragma unroll
    for (int j = 0; j < 4; ++j) { y0[j] = d0[j]*rs*s0[j]+b0[j]; y1[j] = d1[j]*rs*s1[j]+b1[j]; }
    u16x8 ob;
    #pragma unroll
    for (int j = 0; j < 4; ++j) { ob[j] = f2bf(y0[j]); ob[4+j] = f2bf(y1[j]); }
    *(u16x8*)(outb + (size_t)xrow * 512 + c) = ob;
    if (outf) {
        float* of = outf + (size_t)xrow * 512 + c;
        *(f4*)of = y0; *(f4*)(of + 4) = y1;
    }
}

// ---------------------------------------------------------------------------
// All six fp32->bf16 weight/input casts in ONE dispatch (segmented).
// ---------------------------------------------------------------------------
__global__ __launch_bounds__(256) void cast_all_kernel(
    const float* __restrict__ fq,  const float* __restrict__ Wqkv,
    const float* __restrict__ Wo,  const float* __restrict__ W1,
    const float* __restrict__ W2,  const float* __restrict__ Wp,
    unsigned short* fqb, unsigned short* wqA, unsigned short* woA,
    unsigned short* w1A, unsigned short* w2A, unsigned short* wpA)
{
    int i = blockIdx.x * 256 + threadIdx.x;
    const float* src; unsigned short* dst;
    if (i < 1228800)                       { src = fq;   dst = fqb; }
    else if ((i -= 1228800) < 1179648)     { src = Wqkv; dst = wqA; }
    else if ((i -= 1179648) < 393216)      { src = Wo;   dst = woA; }
    else if ((i -= 393216) < 1572864)      { src = W1;   dst = w1A; }
    else if ((i -= 1572864) < 1572864)     { src = W2;   dst = w2A; }
    else if ((i -= 1572864) < 65536)       { src = Wp;   dst = wpA; }
    else return;
    f4 v = ((const f4*)src)[i];
    u16x4 o4 = {f2bf(v[0]), f2bf(v[1]), f2bf(v[2]), f2bf(v[3])};
    ((u16x4*)dst)[i] = o4;
}

// ---------------------------------------------------------------------------
extern "C" void kernel_launch(void* const* d_in, const int* in_sizes, int n_in,
                              void* d_out, int out_size, void* d_ws, size_t ws_size,
                              hipStream_t stream)
{
    const float* fq   = (const float*)d_in[0];
    const float* Wp   = (const float*)d_in[1];
    const float* bp   = (const float*)d_in[2];
    const float* Wqkv = (const float*)d_in[3];
    const float* bqkv = (const float*)d_in[4];
    const float* Wo   = (const float*)d_in[5];
    const float* bo   = (const float*)d_in[6];
    const float* l1s  = (const float*)d_in[7];
    const float* l1b  = (const float*)d_in[8];
    const float* W1   = (const float*)d_in[9];
    const float* b1   = (const float*)d_in[10];
    const float* W2   = (const float*)d_in[11];
    const float* b2   = (const float*)d_in[12];
    const float* l2s  = (const float*)d_in[13];
    const float* l2b  = (const float*)d_in[14];
    float* out = (float*)d_out;

    // Workspace (~117 MB, shorts)
    unsigned short* xb   = (unsigned short*)d_ws;
    unsigned short* qkvb = xb + 4915200;
    unsigned short* hbuf = qkvb + 14745600;
    unsigned short* wbuf = hbuf + 19660800;
    unsigned short* obuf = hbuf;              // alias (dead before W1 writes)
    unsigned short* t1b  = qkvb;              // bf16 delta (qkvb dead post-attn)
    unsigned short* fqb  = hbuf;              // alias (used only at start)
    unsigned short* wqA = wbuf;
    unsigned short* woA = wqA + 4718592;
    unsigned short* w1A = woA + 1572864;
    unsigned short* w2A = w1A + 6291456;
    unsigned short* wpA = w2A + 6291456;

    const dim3 blk(256), blk8(512);
    // XCD-grouped 1-D grids (padded to multiple of 8)
    #define G8(n) dim3((((n) + 7) & ~7))
    // all pre-casts in one dispatch (6012928 f4 units)
    cast_all_kernel<<<dim3(23488), blk, 0, stream>>>(fq, Wqkv, Wo, W1, W2, Wp,
                                                     fqb, wqA, woA, w1A, w2A, wpA);
    // xb = bf16(fq @ Wp^T + bp)
    gemm_bk64<64><<<G8(600), blk, 0, stream>>>(fqb, wpA, bp, nullptr, xb,
                                               9600, 512, 512, 0, 0, 0, 4);

    for (int i = 0; i < 6; ++i) {
        const int rsh = (i & 1) ? 44 : 0;     // (t+44)%48 == (t-4)%48
        const unsigned short* wq = wqA + (size_t)i * 786432;
        const unsigned short* wo = woA + (size_t)i * 262144;
        const unsigned short* w1 = w1A + (size_t)i * 1048576;
        const unsigned short* w2 = w2A + (size_t)i * 1048576;
        // qkvb[rolled] = xb[map] @ Wqkv^T + bqkv, q-cols pre-scaled by 1/8
        gemm_bk64_w8<<<G8(900), blk8, 0, stream>>>(xb, wq, bqkv + i * 1536,
                                                   nullptr, qkvb, 9600, 1536, 512, 0, rsh, 1, 12);
        flash_attn_mfma<<<dim3(960), dim3(320), 0, stream>>>(qkvb, obuf, i & 1);
        // t1b[rolled] = bf16(obuf @ Wo^T + bo)   (qkvb dead -> reuse as t1b)
        gemm_bk64<64><<<G8(600), blk, 0, stream>>>(obuf, wo, bo + i * 512,
                                                   nullptr, t1b, 9600, 512, 512, 0, 0, 0, 4);
        // xb[map] = LN(xb[map] + t1b[rolled])  (folds the roll-back)
        add_ln_kernel<<<dim3(2400), blk, 0, stream>>>(xb, t1b, l1s + i * 512, l1b + i * 512,
                                                      nullptr, xb, rsh);
        // hbuf = relu(xb @ W1^T + b1)   (8-wave BM=128 kernel)
        gemm_bk64_w8<<<G8(1200), blk8, 0, stream>>>(xb, w1, b1 + i * 2048,
                                                    nullptr, hbuf, 9600, 2048, 512, 1, 0, 0, 16);
        // t1b = bf16(hbuf @ W2^T + b2)
        gemm_bk64<64><<<G8(600), blk, 0, stream>>>(hbuf, w2, b2 + i * 512,
                                                   nullptr, t1b, 9600, 512, 2048, 0, 0, 0, 4);
        // xb = LN(xb + t1b); last layer also writes fp32 d_out
        add_ln_kernel<<<dim3(2400), blk, 0, stream>>>(xb, t1b, l2s + i * 512, l2b + i * 512,
                                                      (i == 5) ? out : nullptr, xb, 0);
    }
    #undef G8
}

// Round 15
// 1016.710 us; speedup vs baseline: 1.2170x; 1.0091x over previous
//
#include <hip/hip_runtime.h>

// Problem: B=2, T=48, FQ=100, D=512, H=8, hd=64, DFF=2048, L=6, WSZ=8
// Nw=6, S=800, tokens=9600, windows=12, half=4
//
// Round 24: extend R14's validated mechanism (more waves per barrier domain
// at constant LDS) to the BM=64 GEMM class. gemm_bk64_w8n: 64x128 tile over
// 8 waves of 32x32 (512 threads), LDS 48KB unchanged, barrier count
// unchanged -> 18.75 waves/CU resident (2x the 4-wave form). Used for
// Wo / Wp / W2. qkv/W1 stay on the R14 w8 BM=128 kernel (41.5us measured);
// attention / LN / cast byte-identical to R14 (1026.0us baseline).

typedef float  f4    __attribute__((ext_vector_type(4)));
typedef __bf16 bf8   __attribute__((ext_vector_type(8)));
typedef unsigned short u16x8 __attribute__((ext_vector_type(8)));
typedef unsigned short u16x4 __attribute__((ext_vector_type(4)));
typedef unsigned int   u32x2 __attribute__((ext_vector_type(2)));
typedef unsigned int   u32x4 __attribute__((ext_vector_type(4)));

__device__ __forceinline__ unsigned short f2bf(float f) {
    unsigned int u = __builtin_bit_cast(unsigned int, f);
    u += 0x7fffu + ((u >> 16) & 1u);          // round-to-nearest-even
    return (unsigned short)(u >> 16);
}
__device__ __forceinline__ float bf2f(unsigned short s) {
    return __builtin_bit_cast(float, ((unsigned int)s) << 16);
}

// async global->LDS, 16B per lane; LDS dest = wave-uniform base + lane*16
#define GLD16(gp, lp) __builtin_amdgcn_global_load_lds( \
    (const __attribute__((address_space(1))) void*)(gp), \
    (__attribute__((address_space(3))) void*)(lp), 16, 0, 0)

// rolled row -> source row in x (frame-level roll along T=48, frames of 100)
__device__ __forceinline__ int map_row(int r, int rshift) {
    if (!rshift) return r;
    int bb = r / 4800, rem = r % 4800;
    int tt = rem / 100, f = rem - tt * 100;
    return bb * 4800 + ((tt + rshift) % 48) * 100 + f;
}

// ---------------------------------------------------------------------------
// GEMM (BM=128, 8 waves / 512 threads): BK=64 double-buffer, one barrier per
// K-tile, XCD-grouped 1-D grid. 8 waves of 32x64 (MI=2, NI=4) -> 16 waves/CU
// at 64KB LDS (2 blk/CU). Used for qkv / W1 (R14-validated, 41.5us on W1).
// ---------------------------------------------------------------------------
__global__ __launch_bounds__(512) void gemm_bk64_w8(
    const unsigned short* __restrict__ A, const unsigned short* __restrict__ W,
    const float* __restrict__ bias, float* Cf, unsigned short* Cb,
    int M, int N, int K, int relu, int rshift, int qscale, int NB)
{
    __shared__ unsigned short As[2 * 8192];    // 128 rows x 64 k, swizzled chunks
    __shared__ unsigned short Bs[2 * 8192];
    const int tid = threadIdx.x, lane = tid & 63, wave = tid >> 6;   // 0..7

    const int per = gridDim.x >> 3;
    const int l = (blockIdx.x & 7) * per + (blockIdx.x >> 3);
    const int MB = M / 128;
    if (l >= NB * MB) return;
    const int n0 = (l % NB) * 128, m0 = (l / NB) * 128;

    const unsigned short* ga[2];
    unsigned short* la[2];
    #pragma unroll
    for (int it = 0; it < 2; ++it) {
        int s = it * 512 + tid, row = s >> 3, cg = (s & 7) ^ (row & 7);
        ga[it] = A + (size_t)map_row(m0 + row, rshift) * K + cg * 8;
        la[it] = &As[(it * 512 + wave * 64) * 8];
    }
    const unsigned short* gb[2];
    unsigned short* lb[2];
    #pragma unroll
    for (int it = 0; it < 2; ++it) {
        int s = it * 512 + tid, row = s >> 3, cg = (s & 7) ^ (row & 7);
        gb[it] = W + (size_t)(n0 + row) * K + cg * 8;
        lb[it] = &Bs[(it * 512 + wave * 64) * 8];
    }

    const int wm = (wave >> 1) * 32, wn = (wave & 1) * 64;
    const int lr = lane & 15, quad = lane >> 4;

    f4 acc[2][4];
    #pragma unroll
    for (int i = 0; i < 2; ++i)
        #pragma unroll
        for (int j = 0; j < 4; ++j) acc[i][j] = 0.f;

    #pragma unroll
    for (int it = 0; it < 2; ++it) { GLD16(ga[it], la[it]); GLD16(gb[it], lb[it]); }

    const int NK = K >> 6;
    for (int kt = 0; kt < NK; ++kt) {
        const int cb = kt & 1, nb = cb ^ 1;
        __syncthreads();                   // tile kt resident; buffer nb free
        if (kt + 1 < NK) {
            const int k1 = (kt + 1) << 6;
            #pragma unroll
            for (int it = 0; it < 2; ++it) {
                GLD16(ga[it] + k1, la[it] + nb * 8192);
                GLD16(gb[it] + k1, lb[it] + nb * 8192);
            }
        }
        const unsigned short* Ab = &As[cb * 8192];
        const unsigned short* Bb = &Bs[cb * 8192];
        #pragma unroll
        for (int kh = 0; kh < 2; ++kh) {
            bf8 af[2], bfr[4];
            #pragma unroll
            for (int mi = 0; mi < 2; ++mi) {
                int m = wm + mi * 16 + lr;
                int c = (kh * 4 + quad) ^ (m & 7);
                af[mi] = __builtin_bit_cast(bf8, *(const u16x8*)&Ab[(m * 8 + c) * 8]);
            }
            #pragma unroll
            for (int ni = 0; ni < 4; ++ni) {
                int n = wn + ni * 16 + lr;
                int c = (kh * 4 + quad) ^ (n & 7);
                bfr[ni] = __builtin_bit_cast(bf8, *(const u16x8*)&Bb[(n * 8 + c) * 8]);
            }
            #pragma unroll
            for (int mi = 0; mi < 2; ++mi)
                #pragma unroll
                for (int ni = 0; ni < 4; ++ni)
                    acc[mi][ni] = __builtin_amdgcn_mfma_f32_16x16x32_bf16(
                        af[mi], bfr[ni], acc[mi][ni], 0, 0, 0);
        }
    }

    #pragma unroll
    for (int mi = 0; mi < 2; ++mi) {
        #pragma unroll
        for (int ni = 0; ni < 4; ++ni) {
            const int rowg = m0 + wm + mi * 16 + quad * 4;
            const int colg = n0 + wn + ni * 16 + lr;
            const float bv = bias[colg];
            const float sc = (qscale && colg < 512) ? 0.125f : 1.0f;
            #pragma unroll
            for (int r = 0; r < 4; ++r) {
                float v = (acc[mi][ni][r] + bv) * sc;
                if (relu) v = fmaxf(v, 0.f);
                const size_t off = (size_t)(rowg + r) * N + colg;
                if (Cf) Cf[off] = v;
                if (Cb) Cb[off] = f2bf(v);
            }
        }
    }
}

// ---------------------------------------------------------------------------
// GEMM (BM=64, 8 waves / 512 threads): BK=64 double-buffer, one barrier per
// K-tile, XCD-grouped 1-D grid. 64x128 tile over 8 waves of 32x32
// (2x4 wave grid; MI=2, NI=2), LDS 48KB (3 blk/CU) -> ~19 waves/CU resident
// (2x the 4-wave form). Staging: A = 512 chunks (1 round), B = 1024 (2).
// Used for Wo / Wp / W2.
// ---------------------------------------------------------------------------
__global__ __launch_bounds__(512) void gemm_bk64_w8n(
    const unsigned short* __restrict__ A, const unsigned short* __restrict__ W,
    const float* __restrict__ bias, float* Cf, unsigned short* Cb,
    int M, int N, int K, int relu, int rshift, int qscale, int NB)
{
    __shared__ unsigned short As[2 * 4096];    // 64 rows x 64 k, swizzled chunks
    __shared__ unsigned short Bs[2 * 8192];
    const int tid = threadIdx.x, lane = tid & 63, wave = tid >> 6;   // 0..7

    const int per = gridDim.x >> 3;
    const int l = (blockIdx.x & 7) * per + (blockIdx.x >> 3);
    const int MB = M / 64;
    if (l >= NB * MB) return;
    const int n0 = (l % NB) * 128, m0 = (l / NB) * 64;

    // A staging: 512 chunks over 512 threads, 1 round
    const unsigned short* ga;
    unsigned short* la;
    {
        int s = tid, row = s >> 3, cg = (s & 7) ^ (row & 7);
        ga = A + (size_t)map_row(m0 + row, rshift) * K + cg * 8;
        la = &As[(wave * 64) * 8];
    }
    // B staging: 1024 chunks, 2 rounds
    const unsigned short* gb[2];
    unsigned short* lb[2];
    #pragma unroll
    for (int it = 0; it < 2; ++it) {
        int s = it * 512 + tid, row = s >> 3, cg = (s & 7) ^ (row & 7);
        gb[it] = W + (size_t)(n0 + row) * K + cg * 8;
        lb[it] = &Bs[(it * 512 + wave * 64) * 8];
    }

    const int wm = (wave >> 2) * 32, wn = (wave & 3) * 32;
    const int lr = lane & 15, quad = lane >> 4;

    f4 acc[2][2];
    #pragma unroll
    for (int i = 0; i < 2; ++i)
        #pragma unroll
        for (int j = 0; j < 2; ++j) acc[i][j] = 0.f;

    GLD16(ga, la);
    #pragma unroll
    for (int it = 0; it < 2; ++it) GLD16(gb[it], lb[it]);

    const int NK = K >> 6;
    for (int kt = 0; kt < NK; ++kt) {
        const int cb = kt & 1, nb = cb ^ 1;
        __syncthreads();                   // tile kt resident; buffer nb free
        if (kt + 1 < NK) {
            const int k1 = (kt + 1) << 6;
            GLD16(ga + k1, la + nb * 4096);
            #pragma unroll
            for (int it = 0; it < 2; ++it) GLD16(gb[it] + k1, lb[it] + nb * 8192);
        }
        const unsigned short* Ab = &As[cb * 4096];
        const unsigned short* Bb = &Bs[cb * 8192];
        #pragma unroll
        for (int kh = 0; kh < 2; ++kh) {
            bf8 af[2], bfr[2];
            #pragma unroll
            for (int mi = 0; mi < 2; ++mi) {
                int m = wm + mi * 16 + lr;
                int c = (kh * 4 + quad) ^ (m & 7);
                af[mi] = __builtin_bit_cast(bf8, *(const u16x8*)&Ab[(m * 8 + c) * 8]);
            }
            #pragma unroll
            for (int ni = 0; ni < 2; ++ni) {
                int n = wn + ni * 16 + lr;
                int c = (kh * 4 + quad) ^ (n & 7);
                bfr[ni] = __builtin_bit_cast(bf8, *(const u16x8*)&Bb[(n * 8 + c) * 8]);
            }
            #pragma unroll
            for (int mi = 0; mi < 2; ++mi)
                #pragma unroll
                for (int ni = 0; ni < 2; ++ni)
                    acc[mi][ni] = __builtin_amdgcn_mfma_f32_16x16x32_bf16(
                        af[mi], bfr[ni], acc[mi][ni], 0, 0, 0);
        }
    }

    #pragma unroll
    for (int mi = 0; mi < 2; ++mi) {
        #pragma unroll
        for (int ni = 0; ni < 2; ++ni) {
            const int rowg = m0 + wm + mi * 16 + quad * 4;
            const int colg = n0 + wn + ni * 16 + lr;
            const float bv = bias[colg];
            const float sc = (qscale && colg < 512) ? 0.125f : 1.0f;
            #pragma unroll
            for (int r = 0; r < 4; ++r) {
                float v = (acc[mi][ni][r] + bv) * sc;
                if (relu) v = fmaxf(v, 0.f);
                const size_t off = (size_t)(rowg + r) * N + colg;
                if (Cf) Cf[off] = v;
                if (Cb) Cb[off] = f2bf(v);
            }
        }
    }
}

// ---------------------------------------------------------------------------
// MFMA flash attention (best measured form): max-free softmax, S^T layout,
// KVBLK=32, 5-wave/320-thread blocks, grid 960, XCD-pinned h=bid&7.
// V path: GLD16 into subtiled LDS (pre-swizzled source) + ds_read_b64_tr_b16.
// ---------------------------------------------------------------------------
__global__ __launch_bounds__(320) void flash_attn_mfma(
    const unsigned short* __restrict__ qkv, unsigned short* __restrict__ o,
    int masked)
{
    __shared__ unsigned short Ks[2][2048];                 // K: 32x64, swizzled chunks
    __shared__ __align__(16) unsigned short VTs[2][2048];  // V: subtiled
    __shared__ unsigned short Ps[5][576];                  // per-wave P [q][key] s36

    const int bid = blockIdx.x;
    const int h = bid & 7, kk2 = bid >> 3;
    const int qt = kk2 % 10, w = kk2 / 10;
    const int tid = threadIdx.x, lane = tid & 63, wave = tid >> 6;
    const int lr = lane & 15, quad = lane >> 4;
    const int qb = qt * 80 + wave * 16;
    const size_t wbase = (size_t)w * 800 * 1536;
    const bool do_mask = masked && ((w % 6) == 0);

    // Q B-frags (pre-scaled by 1/8): aQ[kh] = Q[qb+lr][kh*32+quad*8..]
    bf8 aQ[2];
    {
        const unsigned short* qp =
            qkv + wbase + (size_t)(qb + lr) * 1536 + h * 64 + quad * 8;
        aQ[0] = __builtin_bit_cast(bf8, *(const u16x8*)qp);
        aQ[1] = __builtin_bit_cast(bf8, *(const u16x8*)(qp + 32));
    }

    // K staging (waves 0..3): 256 swizzled 16B chunks
    const unsigned short* gk = qkv;
    int kw = 0;
    if (wave < 4) {
        int s = wave * 64 + lane, row = s >> 3, clog = (s & 7) ^ (row & 7);
        gk = qkv + wbase + (size_t)row * 1536 + 512 + h * 64 + clog * 8;
        kw = wave * 512;
    }
    // V staging (waves 0..3): GLD16, pre-swizzled source for subtiled LDS.
    // chunk c = wave*64+lane: S=c>>3 (subtile), wc=c&7:
    //   key = 8*(S&3) + 4*((S>>2)&1) + (wc>>1), dim0 = 16*(S>>3) + 8*(wc&1)
    const unsigned short* gvp = qkv;
    if (wave < 4) {
        int c = wave * 64 + lane, S = c >> 3, wc = c & 7;
        int vkey = 8 * (S & 3) + 4 * ((S >> 2) & 1) + (wc >> 1);
        int vdim = 16 * (S >> 3) + 8 * (wc & 1);
        gvp = qkv + wbase + (size_t)vkey * 1536 + 1024 + h * 64 + vdim;
    }

    // tr-read per-lane LDS address (64-bit slot per lane)
    unsigned vtb;
    {
        auto p3 = (__attribute__((address_space(3))) unsigned short*)&VTs[0][0];
        vtb = (unsigned)(unsigned long long)p3 + (unsigned)(lane << 3);
    }

    float lsum = 0.f;
    f4 oacc[4];
    #pragma unroll
    for (int dt = 0; dt < 4; ++dt) oacc[dt] = 0.f;

    const bool qhl = (qb + lr) >= 400;

    // prologue: stage tile 0 into buffer 0
    if (wave < 4) {
        GLD16(gk, &Ks[0][kw]);
        GLD16(gvp, &VTs[0][wave * 512]);
    }

    for (int kt = 0; kt < 25; ++kt) {
        const int cb = kt & 1, nb = cb ^ 1;
        const int k0 = kt * 32;
        __syncthreads();                     // tile kt resident (vmcnt drained)

        // prefetch tile kt+1 (async, both K and V)
        const bool pf = (kt < 24);
        if (pf && wave < 4) {
            GLD16(gk  + (size_t)(k0 + 32) * 1536, &Ks[nb][kw]);
            GLD16(gvp + (size_t)(k0 + 32) * 1536, &VTs[nb][wave * 512]);
        }

        // S^T: A = K-frags (keys lr / 16+lr), B = Q-frag (shared reads)
        f4 st[2];                            // [keyhalf]
        st[0] = 0.f; st[1] = 0.f;
        __builtin_amdgcn_s_setprio(1);
        #pragma unroll
        for (int kh = 0; kh < 2; ++kh) {
            const int cx = (kh * 4 + quad) ^ (lane & 7);
            bf8 kf0 = __builtin_bit_cast(bf8, *(const u16x8*)&Ks[cb][(lr * 8 + cx) * 8]);
            bf8 kf1 = __builtin_bit_cast(bf8, *(const u16x8*)&Ks[cb][((16 + lr) * 8 + cx) * 8]);
            st[0] = __builtin_amdgcn_mfma_f32_16x16x32_bf16(kf0, aQ[kh], st[0], 0, 0, 0);
            st[1] = __builtin_amdgcn_mfma_f32_16x16x32_bf16(kf1, aQ[kh], st[1], 0, 0, 0);
        }
        __builtin_amdgcn_s_setprio(0);

        // max-free softmax; lane holds q=qb+lr, keys k0+quad*4+r (+16)
        {
            u16x4 pk0, pk1;
            float ls = 0.f;
            #pragma unroll
            for (int r = 0; r < 4; ++r) {
                float a = st[0][r], b = st[1][r];
                if (do_mask) {
                    if (((k0 + quad * 4 + r) >= 400) != qhl)      a -= 1000.f;
                    if (((k0 + 16 + quad * 4 + r) >= 400) != qhl) b -= 1000.f;
                }
                float p0 = __expf(fminf(a, 80.f));
                float p1 = __expf(fminf(b, 80.f));
                ls += p0 + p1;
                pk0[r] = (unsigned short)(__builtin_bit_cast(unsigned int, p0) >> 16);
                pk1[r] = (unsigned short)(__builtin_bit_cast(unsigned int, p1) >> 16);
            }
            lsum += ls;
            *(u16x4*)&Ps[wave][lr * 36 + quad * 4]      = pk0;  // b64 write
            *(u16x4*)&Ps[wave][lr * 36 + 16 + quad * 4] = pk1;  // b64 write
        }

        // PV: aP readback (same wave: ds-ordered) + V fragments via tr reads
        bf8 aP = __builtin_bit_cast(bf8, *(const u16x8*)&Ps[wave][lr * 36 + quad * 8]);
        const unsigned va = vtb + ((unsigned)cb << 12);
        u32x2 t0, t1, t2, t3, t4, t5, t6, t7;
        asm volatile("ds_read_b64_tr_b16 %0, %1"             : "=v"(t0) : "v"(va));
        asm volatile("ds_read_b64_tr_b16 %0, %1 offset:512"  : "=v"(t1) : "v"(va));
        asm volatile("ds_read_b64_tr_b16 %0, %1 offset:1024" : "=v"(t2) : "v"(va));
        asm volatile("ds_read_b64_tr_b16 %0, %1 offset:1536" : "=v"(t3) : "v"(va));
        asm volatile("ds_read_b64_tr_b16 %0, %1 offset:2048" : "=v"(t4) : "v"(va));
        asm volatile("ds_read_b64_tr_b16 %0, %1 offset:2560" : "=v"(t5) : "v"(va));
        asm volatile("ds_read_b64_tr_b16 %0, %1 offset:3072" : "=v"(t6) : "v"(va));
        asm volatile("ds_read_b64_tr_b16 %0, %1 offset:3584" : "=v"(t7) : "v"(va));
        asm volatile("s_waitcnt lgkmcnt(0)" ::: "memory");    // rule #18
        __builtin_amdgcn_sched_barrier(0);
        __builtin_amdgcn_s_setprio(1);
        {
            u32x4 b0 = {t0[0], t0[1], t1[0], t1[1]};
            u32x4 b1 = {t2[0], t2[1], t3[0], t3[1]};
            u32x4 b2 = {t4[0], t4[1], t5[0], t5[1]};
            u32x4 b3 = {t6[0], t6[1], t7[0], t7[1]};
            oacc[0] = __builtin_amdgcn_mfma_f32_16x16x32_bf16(aP, __builtin_bit_cast(bf8, b0), oacc[0], 0, 0, 0);
            oacc[1] = __builtin_amdgcn_mfma_f32_16x16x32_bf16(aP, __builtin_bit_cast(bf8, b1), oacc[1], 0, 0, 0);
            oacc[2] = __builtin_amdgcn_mfma_f32_16x16x32_bf16(aP, __builtin_bit_cast(bf8, b2), oacc[2], 0, 0, 0);
            oacc[3] = __builtin_amdgcn_mfma_f32_16x16x32_bf16(aP, __builtin_bit_cast(bf8, b3), oacc[3], 0, 0, 0);
        }
        __builtin_amdgcn_s_setprio(0);
    }

    // epilogue: l lives per lane-column q=qb+lr; O rows are q=qb+quad*4+r
    {
        float l = lsum;
        l += __shfl_xor(l, 16);
        l += __shfl_xor(l, 32);              // now equal across quads, per lr
        float inv[4];
        #pragma unroll
        for (int r = 0; r < 4; ++r)
            inv[r] = 1.0f / __shfl(l, quad * 4 + r);   // lane (quad*4+r) holds q row
        #pragma unroll
        for (int dt = 0; dt < 4; ++dt)
            #pragma unroll
            for (int r = 0; r < 4; ++r)
                o[((size_t)w * 800 + qb + quad * 4 + r) * 512 + h * 64 + dt * 16 + lr] =
                    f2bf(oacc[dt][r] * inv[r]);
    }
}

// ---------------------------------------------------------------------------
// xb[map(row)] = bf16(LN(xb[map(row)] + dlt[row]) * s + b); optional fp32 out.
// ---------------------------------------------------------------------------
__global__ __launch_bounds__(256) void add_ln_kernel(
    const unsigned short* xb, const unsigned short* dlt,
    const float* __restrict__ s, const float* __restrict__ b,
    float* outf, unsigned short* outb, int rshift)
{
    const int wave = threadIdx.x >> 6, lane = threadIdx.x & 63;
    const int row = blockIdx.x * 4 + wave;
    const int xrow = map_row(row, rshift);
    const int c = lane * 8;
    u16x8 xv = *(const u16x8*)(xb  + (size_t)xrow * 512 + c);
    u16x8 dv = *(const u16x8*)(dlt + (size_t)row  * 512 + c);
    f4 u0, u1;
    #pragma unroll
    for (int j = 0; j < 4; ++j) {
        u0[j] = bf2f(xv[j])     + bf2f(dv[j]);
        u1[j] = bf2f(xv[4 + j]) + bf2f(dv[4 + j]);
    }
    float sum = u0[0]+u0[1]+u0[2]+u0[3] + u1[0]+u1[1]+u1[2]+u1[3];
    #pragma unroll
    for (int o2 = 1; o2 < 64; o2 <<= 1) sum += __shfl_xor(sum, o2);
    const float mu = sum * (1.0f / 512.0f);
    f4 d0 = u0 - mu, d1 = u1 - mu;
    float sq = d0[0]*d0[0]+d0[1]*d0[1]+d0[2]*d0[2]+d0[3]*d0[3]
             + d1[0]*d1[0]+d1[1]*d1[1]+d1[2]*d1[2]+d1[3]*d1[3];
    #pragma unroll
    for (int o2 = 1; o2 < 64; o2 <<= 1) sq += __shfl_xor(sq, o2);
    const float rs = rsqrtf(sq * (1.0f / 512.0f) + 1e-5f);
    f4 s0 = *(const f4*)(s + c), s1 = *(const f4*)(s + c + 4);
    f4 b0 = *(const f4*)(b + c), b1 = *(const f4*)(b + c + 4);
    f4 y0, y1;
    #pragma unroll
    for (int j = 0; j < 4; ++j) { y0[j] = d0[j]*rs*s0[j]+b0[j]; y1[j] = d1[j]*rs*s1[j]+b1[j]; }
    u16x8 ob;
    #pragma unroll
    for (int j = 0; j < 4; ++j) { ob[j] = f2bf(y0[j]); ob[4+j] = f2bf(y1[j]); }
    *(u16x8*)(outb + (size_t)xrow * 512 + c) = ob;
    if (outf) {
        float* of = outf + (size_t)xrow * 512 + c;
        *(f4*)of = y0; *(f4*)(of + 4) = y1;
    }
}

// ---------------------------------------------------------------------------
// All six fp32->bf16 weight/input casts in ONE dispatch (segmented).
// ---------------------------------------------------------------------------
__global__ __launch_bounds__(256) void cast_all_kernel(
    const float* __restrict__ fq,  const float* __restrict__ Wqkv,
    const float* __restrict__ Wo,  const float* __restrict__ W1,
    const float* __restrict__ W2,  const float* __restrict__ Wp,
    unsigned short* fqb, unsigned short* wqA, unsigned short* woA,
    unsigned short* w1A, unsigned short* w2A, unsigned short* wpA)
{
    int i = blockIdx.x * 256 + threadIdx.x;
    const float* src; unsigned short* dst;
    if (i < 1228800)                       { src = fq;   dst = fqb; }
    else if ((i -= 1228800) < 1179648)     { src = Wqkv; dst = wqA; }
    else if ((i -= 1179648) < 393216)      { src = Wo;   dst = woA; }
    else if ((i -= 393216) < 1572864)      { src = W1;   dst = w1A; }
    else if ((i -= 1572864) < 1572864)     { src = W2;   dst = w2A; }
    else if ((i -= 1572864) < 65536)       { src = Wp;   dst = wpA; }
    else return;
    f4 v = ((const f4*)src)[i];
    u16x4 o4 = {f2bf(v[0]), f2bf(v[1]), f2bf(v[2]), f2bf(v[3])};
    ((u16x4*)dst)[i] = o4;
}

// ---------------------------------------------------------------------------
extern "C" void kernel_launch(void* const* d_in, const int* in_sizes, int n_in,
                              void* d_out, int out_size, void* d_ws, size_t ws_size,
                              hipStream_t stream)
{
    const float* fq   = (const float*)d_in[0];
    const float* Wp   = (const float*)d_in[1];
    const float* bp   = (const float*)d_in[2];
    const float* Wqkv = (const float*)d_in[3];
    const float* bqkv = (const float*)d_in[4];
    const float* Wo   = (const float*)d_in[5];
    const float* bo   = (const float*)d_in[6];
    const float* l1s  = (const float*)d_in[7];
    const float* l1b  = (const float*)d_in[8];
    const float* W1   = (const float*)d_in[9];
    const float* b1   = (const float*)d_in[10];
    const float* W2   = (const float*)d_in[11];
    const float* b2   = (const float*)d_in[12];
    const float* l2s  = (const float*)d_in[13];
    const float* l2b  = (const float*)d_in[14];
    float* out = (float*)d_out;

    // Workspace (~117 MB, shorts)
    unsigned short* xb   = (unsigned short*)d_ws;
    unsigned short* qkvb = xb + 4915200;
    unsigned short* hbuf = qkvb + 14745600;
    unsigned short* wbuf = hbuf + 19660800;
    unsigned short* obuf = hbuf;              // alias (dead before W1 writes)
    unsigned short* t1b  = qkvb;              // bf16 delta (qkvb dead post-attn)
    unsigned short* fqb  = hbuf;              // alias (used only at start)
    unsigned short* wqA = wbuf;
    unsigned short* woA = wqA + 4718592;
    unsigned short* w1A = woA + 1572864;
    unsigned short* w2A = w1A + 6291456;
    unsigned short* wpA = w2A + 6291456;

    const dim3 blk(256), blk8(512);
    // XCD-grouped 1-D grids (padded to multiple of 8)
    #define G8(n) dim3((((n) + 7) & ~7))
    // all pre-casts in one dispatch (6012928 f4 units)
    cast_all_kernel<<<dim3(23488), blk, 0, stream>>>(fq, Wqkv, Wo, W1, W2, Wp,
                                                     fqb, wqA, woA, w1A, w2A, wpA);
    // xb = bf16(fq @ Wp^T + bp)
    gemm_bk64_w8n<<<G8(600), blk8, 0, stream>>>(fqb, wpA, bp, nullptr, xb,
                                                9600, 512, 512, 0, 0, 0, 4);

    for (int i = 0; i < 6; ++i) {
        const int rsh = (i & 1) ? 44 : 0;     // (t+44)%48 == (t-4)%48
        const unsigned short* wq = wqA + (size_t)i * 786432;
        const unsigned short* wo = woA + (size_t)i * 262144;
        const unsigned short* w1 = w1A + (size_t)i * 1048576;
        const unsigned short* w2 = w2A + (size_t)i * 1048576;
        // qkvb[rolled] = xb[map] @ Wqkv^T + bqkv, q-cols pre-scaled by 1/8
        gemm_bk64_w8<<<G8(900), blk8, 0, stream>>>(xb, wq, bqkv + i * 1536,
                                                   nullptr, qkvb, 9600, 1536, 512, 0, rsh, 1, 12);
        flash_attn_mfma<<<dim3(960), dim3(320), 0, stream>>>(qkvb, obuf, i & 1);
        // t1b[rolled] = bf16(obuf @ Wo^T + bo)   (qkvb dead -> reuse as t1b)
        gemm_bk64_w8n<<<G8(600), blk8, 0, stream>>>(obuf, wo, bo + i * 512,
                                                    nullptr, t1b, 9600, 512, 512, 0, 0, 0, 4);
        // xb[map] = LN(xb[map] + t1b[rolled])  (folds the roll-back)
        add_ln_kernel<<<dim3(2400), blk, 0, stream>>>(xb, t1b, l1s + i * 512, l1b + i * 512,
                                                      nullptr, xb, rsh);
        // hbuf = relu(xb @ W1^T + b1)   (8-wave BM=128 kernel)
        gemm_bk64_w8<<<G8(1200), blk8, 0, stream>>>(xb, w1, b1 + i * 2048,
                                                    nullptr, hbuf, 9600, 2048, 512, 1, 0, 0, 16);
        // t1b = bf16(hbuf @ W2^T + b2)  (8-wave BM=64 kernel)
        gemm_bk64_w8n<<<G8(600), blk8, 0, stream>>>(hbuf, w2, b2 + i * 512,
                                                    nullptr, t1b, 9600, 512, 2048, 0, 0, 0, 4);
        // xb = LN(xb + t1b); last layer also writes fp32 d_out
        add_ln_kernel<<<dim3(2400), blk, 0, stream>>>(xb, t1b, l2s + i * 512, l2b + i * 512,
                                                      (i == 5) ? out : nullptr, xb, 0);
    }
    #undef G8
}